// Round 5
// baseline (3108.331 us; speedup 1.0000x reference)
//
#include <hip/hip_runtime.h>
#include <climits>

#define NU_ 80000
#define NS_ 20000
#define NM_ 30000
#define UIN_ (NU_ + NS_)
#define DD 128
#define LL 32
#define RPB 64                                   // rows per bucket (power of 2)
#define NCH 64                                   // chunks per graph
#define NBUK_UI ((UIN_ + RPB - 1) / RPB)         // 1563
#define NBUK_MM ((NM_  + RPB - 1) / RPB)         // 469

typedef unsigned int   uint32;
typedef unsigned short ushort16;

__device__ __forceinline__ float bflo(uint32 u) { return __uint_as_float(u << 16); }
__device__ __forceinline__ float bfhi(uint32 u) { return __uint_as_float(u & 0xffff0000u); }
__device__ __forceinline__ ushort16 f2bf(float f) {
    uint32 u = __float_as_uint(f);
    return (ushort16)((u + 0x7fffu + ((u >> 16) & 1u)) >> 16);   // RNE
}
__device__ __forceinline__ uint32 pack2bf(float lo, float hi) {
    return (uint32)f2bf(lo) | ((uint32)f2bf(hi) << 16);
}

// ---------------------------------------------------------------------------
// fp32 (split tables) -> packed bf16 table. n2 = total element pairs.
// ---------------------------------------------------------------------------
__global__ void convert_kernel(const float* __restrict__ srcA, const float* __restrict__ srcB,
                               int split_rows, uint32* __restrict__ dst, size_t n2) {
    size_t stride = (size_t)gridDim.x * blockDim.x;
    const size_t split_e = (size_t)split_rows * DD;
    for (size_t i = (size_t)blockIdx.x * blockDim.x + threadIdx.x; i < n2; i += stride) {
        size_t e = i * 2;
        const float* s = (e < split_e) ? (srcA + e) : (srcB + (e - split_e));
        float2 v = *reinterpret_cast<const float2*>(s);
        dst[i] = pack2bf(v.x, v.y);
    }
}

// ---------------------------------------------------------------------------
// P1: per-chunk bucket histogram, bucket-major output h[b*NCH + c]
// ---------------------------------------------------------------------------
template <int NBUK>
__global__ __launch_bounds__(256) void bucket_hist(const int* __restrict__ rows, int E,
                                                   int csz, int* __restrict__ h) {
    __shared__ int hist[NBUK];
    for (int i = threadIdx.x; i < NBUK; i += 256) hist[i] = 0;
    __syncthreads();
    const int c  = blockIdx.x;
    const int lo = c * csz, hi = min(lo + csz, E);
    for (int i = lo + threadIdx.x; i < hi; i += 256)
        atomicAdd(&hist[rows[i] >> 6], 1);
    __syncthreads();
    for (int b = threadIdx.x; b < NBUK; b += 256)
        h[b * NCH + c] = hist[b];
}

// ---------------------------------------------------------------------------
// P2: multi-block exclusive scan (reused from round 3)
// ---------------------------------------------------------------------------
__global__ __launch_bounds__(256) void scan_blocksum(const int* __restrict__ cnt,
                                                     int* __restrict__ bsum, int n) {
    __shared__ int red[256];
    int base = blockIdx.x * 1024 + threadIdx.x * 4;
    int s = 0;
    if (base + 3 < n) {
        int4 v = *reinterpret_cast<const int4*>(cnt + base);
        s = v.x + v.y + v.z + v.w;
    } else {
        for (int i = base; i < n && i < base + 4; ++i) s += cnt[i];
    }
    red[threadIdx.x] = s;
    __syncthreads();
    for (int off = 128; off >= 1; off >>= 1) {
        if (threadIdx.x < off) red[threadIdx.x] += red[threadIdx.x + off];
        __syncthreads();
    }
    if (threadIdx.x == 0) bsum[blockIdx.x] = red[0];
}

__global__ __launch_bounds__(256) void scan_final(const int* __restrict__ cnt,
                                                  const int* __restrict__ bsum,
                                                  int* __restrict__ row_ptr,
                                                  int* __restrict__ cursor, int n) {
    __shared__ int lds[256];
    __shared__ int blk_off_s;
    const int tid = threadIdx.x;
    const int b   = blockIdx.x;

    int s = 0;
    for (int j = tid; j < b; j += 256) s += bsum[j];
    lds[tid] = s;
    __syncthreads();
    for (int off = 128; off >= 1; off >>= 1) {
        if (tid < off) lds[tid] += lds[tid + off];
        __syncthreads();
    }
    if (tid == 0) blk_off_s = lds[0];
    __syncthreads();
    const int blk_off = blk_off_s;

    int base = b * 1024 + tid * 4;
    int c0 = 0, c1 = 0, c2 = 0, c3 = 0;
    if (base + 3 < n) {
        int4 v = *reinterpret_cast<const int4*>(cnt + base);
        c0 = v.x; c1 = v.y; c2 = v.z; c3 = v.w;
    } else {
        if (base     < n) c0 = cnt[base];
        if (base + 1 < n) c1 = cnt[base + 1];
        if (base + 2 < n) c2 = cnt[base + 2];
        if (base + 3 < n) c3 = cnt[base + 3];
    }
    int tsum = c0 + c1 + c2 + c3;
    __syncthreads();
    lds[tid] = tsum;
    __syncthreads();
    for (int off = 1; off < 256; off <<= 1) {
        int v = (tid >= off) ? lds[tid - off] : 0;
        __syncthreads();
        lds[tid] += v;
        __syncthreads();
    }
    int p0 = blk_off + ((tid > 0) ? lds[tid - 1] : 0);
    int p1 = p0 + c0, p2 = p1 + c1, p3 = p2 + c2, p4 = p3 + c3;

    if (base     < n) { row_ptr[base]     = p0; cursor[base]     = p0; if (base     == n - 1) row_ptr[n] = p1; }
    if (base + 1 < n) { row_ptr[base + 1] = p1; cursor[base + 1] = p1; if (base + 1 == n - 1) row_ptr[n] = p2; }
    if (base + 2 < n) { row_ptr[base + 2] = p2; cursor[base + 2] = p2; if (base + 2 == n - 1) row_ptr[n] = p3; }
    if (base + 3 < n) { row_ptr[base + 3] = p3; cursor[base + 3] = p3; if (base + 3 == n - 1) row_ptr[n] = p4; }
}

// ---------------------------------------------------------------------------
// P3: per-chunk scatter into bucket-grouped cv. LDS cursors seeded from the
// scanned (bucket-major) offsets -> per-(chunk,bucket) writes are contiguous.
// cv entry: x = col | (row_local << 25), y = val bits.
// ---------------------------------------------------------------------------
template <int NBUK>
__global__ __launch_bounds__(256) void bucket_scatter(
    const int* __restrict__ rows, const int* __restrict__ cols,
    const float* __restrict__ vals, const int* __restrict__ scanned,
    int E, int csz, uint2* __restrict__ cv) {
    __shared__ int cur[NBUK];
    const int c = blockIdx.x;
    for (int b = threadIdx.x; b < NBUK; b += 256) cur[b] = scanned[b * NCH + c];
    __syncthreads();
    const int lo = c * csz, hi = min(lo + csz, E);
    for (int i = lo + threadIdx.x; i < hi; i += 256) {
        int r = rows[i];
        int b = r >> 6;
        int pos = atomicAdd(&cur[b], 1);
        cv[pos] = make_uint2((uint32)cols[i] | ((uint32)(r & 63) << 25),
                             __float_as_uint(vals[i]));
    }
}

// ---------------------------------------------------------------------------
// P4: bucket pull. One block per 64-row bucket; 32KB LDS fp32 accumulator.
// Wave per edge (4-edge unroll); lane owns dims 2l,2l+1. MODE bit0: d_inv
// scale. MODE bit1: out = (orig + hprev + res)/3. bf16 in/out.
// ---------------------------------------------------------------------------
template <int MODE>
__global__ __launch_bounds__(256) void pull_bucket(
    const int* __restrict__ scanned, const uint2* __restrict__ cv,
    const ushort16* __restrict__ x, const float* __restrict__ d_inv,
    const ushort16* __restrict__ orig, const ushort16* __restrict__ hprev,
    ushort16* __restrict__ out, int nrows)
{
    __shared__ float acc[RPB * DD];                  // 32 KB
    const int b    = blockIdx.x;
    const int tid  = threadIdx.x;
    const int lane = tid & 63;
    const int w    = tid >> 6;

    for (int i = tid; i < RPB * DD; i += 256) acc[i] = 0.f;
    __syncthreads();

    const int beg = scanned[b * NCH];
    const int end = scanned[(b + 1) * NCH];

    for (int e0 = beg + w * 4; e0 < end; e0 += 16) {
        const int ne = min(4, end - e0);             // wave-uniform
        uint2  p[4];
        uint32 g[4];
        #pragma unroll 4
        for (int k = 0; k < 4; ++k) {
            if (k < ne) {
                p[k] = cv[e0 + k];
                uint32 col = p[k].x & 0x1FFFFFFu;
                g[k] = *reinterpret_cast<const uint32*>(x + ((size_t)col << 7) + lane * 2);
            }
        }
        #pragma unroll 4
        for (int k = 0; k < 4; ++k) {
            if (k < ne) {
                float v  = __uint_as_float(p[k].y);
                int   rl = (int)(p[k].x >> 25);
                atomicAdd(&acc[rl * DD + lane * 2],     v * bflo(g[k]));
                atomicAdd(&acc[rl * DD + lane * 2 + 1], v * bfhi(g[k]));
            }
        }
    }
    __syncthreads();

    const int grow0 = b * RPB;
    for (int i = tid; i < RPB * (DD / 2); i += 256) {
        int rl   = i >> 6;
        int grow = grow0 + rl;
        if (grow >= nrows) break;                    // rl monotone per thread
        int dp = (i & 63) * 2;
        float lo = acc[rl * DD + dp], hi = acc[rl * DD + dp + 1];
        if (MODE & 1) { float s = d_inv[grow]; lo *= s; hi *= s; }
        if (MODE & 2) {
            const float inv3 = 1.0f / 3.0f;
            uint32 o  = *reinterpret_cast<const uint32*>(orig  + ((size_t)grow << 7) + dp);
            uint32 hh = *reinterpret_cast<const uint32*>(hprev + ((size_t)grow << 7) + dp);
            lo = (bflo(o) + bflo(hh) + lo) * inv3;
            hi = (bfhi(o) + bfhi(hh) + hi) * inv3;
        }
        *reinterpret_cast<uint32*>(out + ((size_t)grow << 7) + dp) = pack2bf(lo, hi);
    }
}

// ---------------------------------------------------------------------------
// Attention + prediction tail: one block (512 threads) per batch element.
// ---------------------------------------------------------------------------
__global__ __launch_bounds__(512) void attn_pred_kernel(
    const int* __restrict__ mashup_inputs, const int* __restrict__ service_inputs,
    const int* __restrict__ member_masked, const float* __restrict__ mask,
    const ushort16* __restrict__ ui_final, const ushort16* __restrict__ mash_final,
    const float* __restrict__ att_w1, const float* __restrict__ att_b1,
    const float* __restrict__ att_w2, const float* __restrict__ att_b2,
    const float* __restrict__ pred_w1, const float* __restrict__ pred_b1,
    const float* __restrict__ pred_w2, const float* __restrict__ pred_b2,
    float* __restrict__ out)
{
    const int b   = blockIdx.x;
    const int tid = threadIdx.x;

    __shared__ float mem_lds[LL * 129];
    __shared__ float svc_lds[DD];
    __shared__ float mash_lds[DD];
    __shared__ float w1_lds[2 * DD * 16];
    __shared__ float hdnw_lds[LL * 16];
    __shared__ float wt_lds[LL];
    __shared__ float new_lds[3 * DD];
    __shared__ float hp_lds[8];
    __shared__ int   midx[LL];

    if (tid < LL) midx[tid] = member_masked[b * LL + tid];
    for (int i = tid; i < 2 * DD * 16; i += 512) w1_lds[i] = att_w1[i];
    if (tid < 64) {
        int sidx = service_inputs[b];
        uint32 u = *reinterpret_cast<const uint32*>(ui_final + (size_t)(NU_ + sidx) * DD + tid * 2);
        svc_lds[tid * 2]     = bflo(u);
        svc_lds[tid * 2 + 1] = bfhi(u);
    } else if (tid >= 448) {
        int t  = tid - 448;
        int mi = mashup_inputs[b];
        uint32 u = *reinterpret_cast<const uint32*>(mash_final + (size_t)mi * DD + t * 2);
        mash_lds[t * 2]     = bflo(u);
        mash_lds[t * 2 + 1] = bfhi(u);
    }
    __syncthreads();

    for (int i = tid; i < LL * 64; i += 512) {
        int l = i >> 6, dp = (i & 63) * 2;
        uint32 u = *reinterpret_cast<const uint32*>(ui_final + (size_t)midx[l] * DD + dp);
        mem_lds[l * 129 + dp]     = bflo(u);
        mem_lds[l * 129 + dp + 1] = bfhi(u);
    }
    __syncthreads();

    {
        int l = tid >> 4, j = tid & 15;
        float acc = att_b1[j];
        const float* m = &mem_lds[l * 129];
        #pragma unroll 4
        for (int k = 0; k < DD; ++k) acc += m[k] * w1_lds[k * 16 + j];
        #pragma unroll 4
        for (int k = 0; k < DD; ++k) acc += svc_lds[k] * w1_lds[(DD + k) * 16 + j];
        acc = fmaxf(acc, 0.0f);
        hdnw_lds[l * 16 + j] = acc * att_w2[j];
    }
    __syncthreads();

    if (tid < 64) {
        float s = -3.0e38f;
        if (tid < LL) {
            s = att_b2[0];
            for (int j = 0; j < 16; ++j) s += hdnw_lds[tid * 16 + j];
            if (mask[b * LL + tid] > 0.0f) s = -1.0e9f;
        }
        float mx = s;
        for (int off = 16; off >= 1; off >>= 1) mx = fmaxf(mx, __shfl_xor(mx, off));
        float ex = (tid < LL) ? __expf(s - mx) : 0.0f;
        float sum = ex;
        for (int off = 16; off >= 1; off >>= 1) sum += __shfl_xor(sum, off);
        if (tid < LL) wt_lds[tid] = ex / sum;
    }
    __syncthreads();

    if (tid < DD) {
        float g = 0.0f;
        #pragma unroll 4
        for (int l = 0; l < LL; ++l) g += wt_lds[l] * mem_lds[l * 129 + tid];
        float me = g + mash_lds[tid];
        float sv = svc_lds[tid];
        new_lds[tid]          = me * sv;
        new_lds[DD + tid]     = me;
        new_lds[2 * DD + tid] = sv;
    }
    __syncthreads();

    if (tid < 8) {
        float acc = pred_b1[tid];
        for (int k = 0; k < 3 * DD; ++k) acc += new_lds[k] * pred_w1[k * 8 + tid];
        acc = fmaxf(acc, 0.0f);
        hp_lds[tid] = acc * pred_w2[tid];
    }
    __syncthreads();

    if (tid == 0) {
        float z = pred_b2[0];
        for (int j = 0; j < 8; ++j) z += hp_lds[j];
        out[b] = 1.0f / (1.0f + __expf(-z));
    }
}

// ---------------------------------------------------------------------------
extern "C" void kernel_launch(void* const* d_in, const int* in_sizes, int n_in,
                              void* d_out, int out_size, void* d_ws, size_t ws_size,
                              hipStream_t stream) {
    const int*   mashup_inputs  = (const int*)  d_in[0];
    const int*   service_inputs = (const int*)  d_in[1];
    const int*   member_masked  = (const int*)  d_in[2];
    const float* mask           = (const float*)d_in[3];
    const int*   adj_rows       = (const int*)  d_in[4];
    const int*   adj_cols       = (const int*)  d_in[5];
    const float* adj_vals       = (const float*)d_in[6];
    const int*   A_rows         = (const int*)  d_in[7];
    const int*   A_cols         = (const int*)  d_in[8];
    const float* A_vals         = (const float*)d_in[9];
    const float* d_inv          = (const float*)d_in[10];
    const float* user_tbl       = (const float*)d_in[11];
    const float* service_tbl    = (const float*)d_in[12];
    const float* mashup_tbl     = (const float*)d_in[13];
    const float* att_w1         = (const float*)d_in[14];
    const float* att_b1         = (const float*)d_in[15];
    const float* att_w2         = (const float*)d_in[16];
    const float* att_b2         = (const float*)d_in[17];
    const float* pred_w1        = (const float*)d_in[18];
    const float* pred_b1        = (const float*)d_in[19];
    const float* pred_w2        = (const float*)d_in[20];
    const float* pred_b2        = (const float*)d_in[21];

    const int E_ui = in_sizes[4];
    const int E_mm = in_sizes[7];
    const int B    = in_sizes[0];

    const int N_UI   = NBUK_UI * NCH;                  // 100032
    const int N_MM   = NBUK_MM * NCH;                  // 30016
    const int NB_UI  = (N_UI + 1023) / 1024;           // 98
    const int NB_MM  = (N_MM + 1023) / 1024;           // 30
    const int csz_ui = (E_ui + NCH - 1) / NCH;
    const int csz_mm = (E_mm + NCH - 1) / NCH;

    // ---- workspace layout ----
    uint2*    ui_cv   = (uint2*)d_ws;                          // E_ui
    uint2*    mm_cv   = ui_cv + E_ui;                          // E_mm
    int*      h_ui    = (int*)(mm_cv + E_mm);                  // N_UI
    int*      hs_ui   = h_ui  + N_UI;                          // N_UI+1 (pad 4)
    int*      h_mm    = hs_ui + N_UI + 4;                      // N_MM
    int*      hs_mm   = h_mm  + N_MM;                          // N_MM+1 (pad 4)
    int*      bs      = hs_mm + N_MM + 4;                      // 128
    ushort16* ui_bf   = (ushort16*)(bs + 128);                 // UIN*128
    ushort16* h1      = ui_bf + (size_t)UIN_ * DD;
    ushort16* h2      = h1    + (size_t)UIN_ * DD;             // ui_final
    ushort16* mash_bf = h2    + (size_t)UIN_ * DD;
    ushort16* m1      = mash_bf + (size_t)NM_ * DD;
    ushort16* m2      = m1    + (size_t)NM_ * DD;              // mash_final

    // ---- bf16 conversion of base tables ----
    convert_kernel<<<2048, 256, 0, stream>>>(user_tbl, service_tbl, NU_,
                                             (uint32*)ui_bf, (size_t)UIN_ * DD / 2);
    convert_kernel<<<1024, 256, 0, stream>>>(mashup_tbl, mashup_tbl, NM_,
                                             (uint32*)mash_bf, (size_t)NM_ * DD / 2);

    // ---- bucket-grouped edge build: UI ----
    bucket_hist<NBUK_UI><<<NCH, 256, 0, stream>>>(adj_rows, E_ui, csz_ui, h_ui);
    scan_blocksum<<<NB_UI, 256, 0, stream>>>(h_ui, bs, N_UI);
    scan_final<<<NB_UI, 256, 0, stream>>>(h_ui, bs, hs_ui, h_ui, N_UI);
    bucket_scatter<NBUK_UI><<<NCH, 256, 0, stream>>>(adj_rows, adj_cols, adj_vals,
                                                     hs_ui, E_ui, csz_ui, ui_cv);
    // ---- bucket-grouped edge build: MM ----
    bucket_hist<NBUK_MM><<<NCH, 256, 0, stream>>>(A_rows, E_mm, csz_mm, h_mm);
    scan_blocksum<<<NB_MM, 256, 0, stream>>>(h_mm, bs, N_MM);
    scan_final<<<NB_MM, 256, 0, stream>>>(h_mm, bs, hs_mm, h_mm, N_MM);
    bucket_scatter<NBUK_MM><<<NCH, 256, 0, stream>>>(A_rows, A_cols, A_vals,
                                                     hs_mm, E_mm, csz_mm, mm_cv);

    // ---- user/service LightGCN propagation (2 layers) ----
    pull_bucket<0><<<NBUK_UI, 256, 0, stream>>>(
        hs_ui, ui_cv, ui_bf, nullptr, nullptr, nullptr, h1, UIN_);
    pull_bucket<2><<<NBUK_UI, 256, 0, stream>>>(
        hs_ui, ui_cv, h1, nullptr, ui_bf, h1, h2, UIN_);

    // ---- mashup propagation (2 layers, d_inv fused) ----
    pull_bucket<1><<<NBUK_MM, 256, 0, stream>>>(
        hs_mm, mm_cv, mash_bf, d_inv, nullptr, nullptr, m1, NM_);
    pull_bucket<3><<<NBUK_MM, 256, 0, stream>>>(
        hs_mm, mm_cv, m1, d_inv, mash_bf, m1, m2, NM_);

    // ---- attention + prediction tail ----
    attn_pred_kernel<<<B, 512, 0, stream>>>(
        mashup_inputs, service_inputs, member_masked, mask,
        h2, m2,
        att_w1, att_b1, att_w2, att_b2,
        pred_w1, pred_b1, pred_w2, pred_b2,
        (float*)d_out);
}

// Round 6
// 395.226 us; speedup vs baseline: 7.8647x; 7.8647x over previous
//
#include <hip/hip_runtime.h>
#include <climits>

#define NU_ 80000
#define NS_ 20000
#define NM_ 30000
#define UIN_ (NU_ + NS_)
#define DD 128
#define LL 32
#define RPB 64                                   // rows per bucket
#define NCH 64                                   // chunks per graph
#define NBUK_UI ((UIN_ + RPB - 1) / RPB)         // 1563
#define NBUK_MM ((NM_  + RPB - 1) / RPB)         // 469
// NOTE: UIN_%64==32, NM_%64==48 (both !=0) -> row_ptr[n] sentinel comes from
// the last bucket's zero-count padding rows in sort_bucket.

typedef unsigned int   uint32;
typedef unsigned short ushort16;

__device__ __forceinline__ float bflo(uint32 u) { return __uint_as_float(u << 16); }
__device__ __forceinline__ float bfhi(uint32 u) { return __uint_as_float(u & 0xffff0000u); }
__device__ __forceinline__ ushort16 f2bf(float f) {
    uint32 u = __float_as_uint(f);
    return (ushort16)((u + 0x7fffu + ((u >> 16) & 1u)) >> 16);   // RNE
}
__device__ __forceinline__ uint32 pack2bf(float lo, float hi) {
    return (uint32)f2bf(lo) | ((uint32)f2bf(hi) << 16);
}

// ---------------------------------------------------------------------------
// fp32 (split tables) -> packed bf16 table. n2 = total element pairs.
// ---------------------------------------------------------------------------
__global__ void convert_kernel(const float* __restrict__ srcA, const float* __restrict__ srcB,
                               int split_rows, uint32* __restrict__ dst, size_t n2) {
    size_t stride = (size_t)gridDim.x * blockDim.x;
    const size_t split_e = (size_t)split_rows * DD;
    for (size_t i = (size_t)blockIdx.x * blockDim.x + threadIdx.x; i < n2; i += stride) {
        size_t e = i * 2;
        const float* s = (e < split_e) ? (srcA + e) : (srcB + (e - split_e));
        float2 v = *reinterpret_cast<const float2*>(s);
        dst[i] = pack2bf(v.x, v.y);
    }
}

// ---------------------------------------------------------------------------
// Stage 1: per-chunk bucket histogram, bucket-major output h[b*NCH + c].
// Self-initializing (every slot written) -> no memset needed.
// ---------------------------------------------------------------------------
template <int NBUK>
__global__ __launch_bounds__(256) void bucket_histA(const int* __restrict__ rows, int E,
                                                    int csz, int* __restrict__ h) {
    __shared__ int hist[NBUK];
    for (int i = threadIdx.x; i < NBUK; i += 256) hist[i] = 0;
    __syncthreads();
    const int c  = blockIdx.x;
    const int lo = c * csz, hi = min(lo + csz, E);
    for (int i = lo + threadIdx.x; i < hi; i += 256)
        atomicAdd(&hist[rows[i] >> 6], 1);
    __syncthreads();
    for (int b = threadIdx.x; b < NBUK; b += 256)
        h[b * NCH + c] = hist[b];
}

// ---------------------------------------------------------------------------
// Stage 2: multi-block exclusive scan (from round 3). Writes scan to row_ptr
// and cursor (we pass the same pointer twice); sentinel at [n].
// ---------------------------------------------------------------------------
__global__ __launch_bounds__(256) void scan_blocksum(const int* __restrict__ cnt,
                                                     int* __restrict__ bsum, int n) {
    __shared__ int red[256];
    int base = blockIdx.x * 1024 + threadIdx.x * 4;
    int s = 0;
    if (base + 3 < n) {
        int4 v = *reinterpret_cast<const int4*>(cnt + base);
        s = v.x + v.y + v.z + v.w;
    } else {
        for (int i = base; i < n && i < base + 4; ++i) s += cnt[i];
    }
    red[threadIdx.x] = s;
    __syncthreads();
    for (int off = 128; off >= 1; off >>= 1) {
        if (threadIdx.x < off) red[threadIdx.x] += red[threadIdx.x + off];
        __syncthreads();
    }
    if (threadIdx.x == 0) bsum[blockIdx.x] = red[0];
}

__global__ __launch_bounds__(256) void scan_final(const int* __restrict__ cnt,
                                                  const int* __restrict__ bsum,
                                                  int* __restrict__ row_ptr,
                                                  int* __restrict__ cursor, int n) {
    __shared__ int lds[256];
    __shared__ int blk_off_s;
    const int tid = threadIdx.x;
    const int b   = blockIdx.x;

    int s = 0;
    for (int j = tid; j < b; j += 256) s += bsum[j];
    lds[tid] = s;
    __syncthreads();
    for (int off = 128; off >= 1; off >>= 1) {
        if (tid < off) lds[tid] += lds[tid + off];
        __syncthreads();
    }
    if (tid == 0) blk_off_s = lds[0];
    __syncthreads();
    const int blk_off = blk_off_s;

    int base = b * 1024 + tid * 4;
    int c0 = 0, c1 = 0, c2 = 0, c3 = 0;
    if (base + 3 < n) {
        int4 v = *reinterpret_cast<const int4*>(cnt + base);
        c0 = v.x; c1 = v.y; c2 = v.z; c3 = v.w;
    } else {
        if (base     < n) c0 = cnt[base];
        if (base + 1 < n) c1 = cnt[base + 1];
        if (base + 2 < n) c2 = cnt[base + 2];
        if (base + 3 < n) c3 = cnt[base + 3];
    }
    int tsum = c0 + c1 + c2 + c3;
    __syncthreads();
    lds[tid] = tsum;
    __syncthreads();
    for (int off = 1; off < 256; off <<= 1) {
        int v = (tid >= off) ? lds[tid - off] : 0;
        __syncthreads();
        lds[tid] += v;
        __syncthreads();
    }
    int p0 = blk_off + ((tid > 0) ? lds[tid - 1] : 0);
    int p1 = p0 + c0, p2 = p1 + c1, p3 = p2 + c2, p4 = p3 + c3;

    if (base     < n) { row_ptr[base]     = p0; cursor[base]     = p0; if (base     == n - 1) row_ptr[n] = p1; }
    if (base + 1 < n) { row_ptr[base + 1] = p1; cursor[base + 1] = p1; if (base + 1 == n - 1) row_ptr[n] = p2; }
    if (base + 2 < n) { row_ptr[base + 2] = p2; cursor[base + 2] = p2; if (base + 2 == n - 1) row_ptr[n] = p3; }
    if (base + 3 < n) { row_ptr[base + 3] = p3; cursor[base + 3] = p3; if (base + 3 == n - 1) row_ptr[n] = p4; }
}

// ---------------------------------------------------------------------------
// Stage 3: per-chunk scatter into bucket-grouped cvA. LDS cursors seeded from
// the scanned bucket-major offsets -> per-(chunk,bucket) writes contiguous
// (~15-edge / 120B runs; measured ~1.15-1.3x write amp in round 5).
// cvA entry: x = col | (row_local << 25), y = val bits.
// ---------------------------------------------------------------------------
template <int NBUK>
__global__ __launch_bounds__(256) void bucket_scatterA(
    const int* __restrict__ rows, const int* __restrict__ cols,
    const float* __restrict__ vals, const int* __restrict__ s,
    int E, int csz, uint2* __restrict__ cvA) {
    __shared__ int cur[NBUK];
    const int c = blockIdx.x;
    for (int b = threadIdx.x; b < NBUK; b += 256) cur[b] = s[b * NCH + c];
    __syncthreads();
    const int lo = c * csz, hi = min(lo + csz, E);
    for (int i = lo + threadIdx.x; i < hi; i += 256) {
        int r = rows[i];
        int b = r >> 6;
        int pos = atomicAdd(&cur[b], 1);
        cvA[pos] = make_uint2((uint32)cols[i] | ((uint32)(r & 63) << 25),
                              __float_as_uint(vals[i]));
    }
}

// ---------------------------------------------------------------------------
// Stage 4: exact per-row sort within each bucket. One block per bucket:
// count 64 rows in LDS -> wave-0 shfl exclusive scan -> write row_ptr ->
// scatter into cvB (all writes inside the bucket's ~8KB L2-hot window).
// ---------------------------------------------------------------------------
__global__ __launch_bounds__(256) void sort_bucket(
    const uint2* __restrict__ cvA, const int* __restrict__ s,
    uint2* __restrict__ cvB, int* __restrict__ row_ptr, int nrows) {
    __shared__ int cnt[RPB];
    __shared__ int cur[RPB];
    const int b    = blockIdx.x;
    const int tid  = threadIdx.x;
    const int base = s[b * NCH];
    const int endb = s[(b + 1) * NCH];   // last bucket: sentinel s[NBUK*NCH]=E

    if (tid < RPB) cnt[tid] = 0;
    __syncthreads();
    for (int i = base + tid; i < endb; i += 256)
        atomicAdd(&cnt[cvA[i].x >> 25], 1);
    __syncthreads();
    if (tid < 64) {
        int c = cnt[tid];
        int x = c;
        #pragma unroll
        for (int off = 1; off < 64; off <<= 1) {
            int v = __shfl_up(x, off);
            if (tid >= off) x += v;
        }
        int excl = base + x - c;            // exclusive prefix + bucket base
        cur[tid] = excl;
        int grow = b * RPB + tid;
        if (grow <= nrows) row_ptr[grow] = excl;   // padding rows give row_ptr[n]=E
    }
    __syncthreads();
    for (int i = base + tid; i < endb; i += 256) {
        uint2 e = cvA[i];
        int rl  = (int)(e.x >> 25);
        int pos = atomicAdd(&cur[rl], 1);
        cvB[pos] = make_uint2(e.x & 0x1FFFFFFu, e.y);
    }
}

// ---------------------------------------------------------------------------
// Pull SpMM (bf16 tables): one wave per destination row, lane owns dims 2l,2l+1.
// MODE bit0: scale by d_inv[row]. MODE bit1: out=(orig+hprev+res)/3.
// ---------------------------------------------------------------------------
template <int MODE>
__global__ __launch_bounds__(256) void pull_kernel(
    const int* __restrict__ row_ptr, const uint2* __restrict__ cv,
    const ushort16* __restrict__ x,
    const float* __restrict__ d_inv,
    const ushort16* __restrict__ orig, const ushort16* __restrict__ hprev,
    ushort16* __restrict__ out, int n)
{
    const int wid  = (blockIdx.x * blockDim.x + threadIdx.x) >> 6;
    const int lane = threadIdx.x & 63;
    if (wid >= n) return;
    const int beg = row_ptr[wid];
    const int end = row_ptr[wid + 1];

    float ax0 = 0.f, ay0 = 0.f, ax1 = 0.f, ay1 = 0.f;
    float ax2 = 0.f, ay2 = 0.f, ax3 = 0.f, ay3 = 0.f;
    int e = beg;
    for (; e + 3 < end; e += 4) {
        uint2 p0 = cv[e],     p1 = cv[e + 1];
        uint2 p2 = cv[e + 2], p3 = cv[e + 3];
        uint32 g0 = *reinterpret_cast<const uint32*>(x + (((size_t)p0.x) << 7) + lane * 2);
        uint32 g1 = *reinterpret_cast<const uint32*>(x + (((size_t)p1.x) << 7) + lane * 2);
        uint32 g2 = *reinterpret_cast<const uint32*>(x + (((size_t)p2.x) << 7) + lane * 2);
        uint32 g3 = *reinterpret_cast<const uint32*>(x + (((size_t)p3.x) << 7) + lane * 2);
        float v0 = __uint_as_float(p0.y), v1 = __uint_as_float(p1.y);
        float v2 = __uint_as_float(p2.y), v3 = __uint_as_float(p3.y);
        ax0 += v0 * bflo(g0); ay0 += v0 * bfhi(g0);
        ax1 += v1 * bflo(g1); ay1 += v1 * bfhi(g1);
        ax2 += v2 * bflo(g2); ay2 += v2 * bfhi(g2);
        ax3 += v3 * bflo(g3); ay3 += v3 * bfhi(g3);
    }
    for (; e < end; ++e) {
        uint2 p0 = cv[e];
        uint32 g0 = *reinterpret_cast<const uint32*>(x + (((size_t)p0.x) << 7) + lane * 2);
        float v0 = __uint_as_float(p0.y);
        ax0 += v0 * bflo(g0); ay0 += v0 * bfhi(g0);
    }
    float accx = (ax0 + ax1) + (ax2 + ax3);
    float accy = (ay0 + ay1) + (ay2 + ay3);

    if (MODE & 1) { float s = d_inv[wid]; accx *= s; accy *= s; }
    if (MODE & 2) {
        const float inv3 = 1.0f / 3.0f;
        uint32 o = *reinterpret_cast<const uint32*>(orig  + (((size_t)wid) << 7) + lane * 2);
        uint32 h = *reinterpret_cast<const uint32*>(hprev + (((size_t)wid) << 7) + lane * 2);
        accx = (bflo(o) + bflo(h) + accx) * inv3;
        accy = (bfhi(o) + bfhi(h) + accy) * inv3;
    }
    *reinterpret_cast<uint32*>(out + (((size_t)wid) << 7) + lane * 2) = pack2bf(accx, accy);
}

// ---------------------------------------------------------------------------
// Attention + prediction tail: one block (512 threads) per batch element.
// ---------------------------------------------------------------------------
__global__ __launch_bounds__(512) void attn_pred_kernel(
    const int* __restrict__ mashup_inputs, const int* __restrict__ service_inputs,
    const int* __restrict__ member_masked, const float* __restrict__ mask,
    const ushort16* __restrict__ ui_final, const ushort16* __restrict__ mash_final,
    const float* __restrict__ att_w1, const float* __restrict__ att_b1,
    const float* __restrict__ att_w2, const float* __restrict__ att_b2,
    const float* __restrict__ pred_w1, const float* __restrict__ pred_b1,
    const float* __restrict__ pred_w2, const float* __restrict__ pred_b2,
    float* __restrict__ out)
{
    const int b   = blockIdx.x;
    const int tid = threadIdx.x;

    __shared__ float mem_lds[LL * 129];
    __shared__ float svc_lds[DD];
    __shared__ float mash_lds[DD];
    __shared__ float w1_lds[2 * DD * 16];
    __shared__ float hdnw_lds[LL * 16];
    __shared__ float wt_lds[LL];
    __shared__ float new_lds[3 * DD];
    __shared__ float hp_lds[8];
    __shared__ int   midx[LL];

    if (tid < LL) midx[tid] = member_masked[b * LL + tid];
    for (int i = tid; i < 2 * DD * 16; i += 512) w1_lds[i] = att_w1[i];
    if (tid < 64) {
        int sidx = service_inputs[b];
        uint32 u = *reinterpret_cast<const uint32*>(ui_final + (size_t)(NU_ + sidx) * DD + tid * 2);
        svc_lds[tid * 2]     = bflo(u);
        svc_lds[tid * 2 + 1] = bfhi(u);
    } else if (tid >= 448) {
        int t  = tid - 448;
        int mi = mashup_inputs[b];
        uint32 u = *reinterpret_cast<const uint32*>(mash_final + (size_t)mi * DD + t * 2);
        mash_lds[t * 2]     = bflo(u);
        mash_lds[t * 2 + 1] = bfhi(u);
    }
    __syncthreads();

    for (int i = tid; i < LL * 64; i += 512) {
        int l = i >> 6, dp = (i & 63) * 2;
        uint32 u = *reinterpret_cast<const uint32*>(ui_final + (size_t)midx[l] * DD + dp);
        mem_lds[l * 129 + dp]     = bflo(u);
        mem_lds[l * 129 + dp + 1] = bfhi(u);
    }
    __syncthreads();

    {
        int l = tid >> 4, j = tid & 15;
        float acc = att_b1[j];
        const float* m = &mem_lds[l * 129];
        #pragma unroll 4
        for (int k = 0; k < DD; ++k) acc += m[k] * w1_lds[k * 16 + j];
        #pragma unroll 4
        for (int k = 0; k < DD; ++k) acc += svc_lds[k] * w1_lds[(DD + k) * 16 + j];
        acc = fmaxf(acc, 0.0f);
        hdnw_lds[l * 16 + j] = acc * att_w2[j];
    }
    __syncthreads();

    if (tid < 64) {
        float s = -3.0e38f;
        if (tid < LL) {
            s = att_b2[0];
            for (int j = 0; j < 16; ++j) s += hdnw_lds[tid * 16 + j];
            if (mask[b * LL + tid] > 0.0f) s = -1.0e9f;
        }
        float mx = s;
        for (int off = 16; off >= 1; off >>= 1) mx = fmaxf(mx, __shfl_xor(mx, off));
        float ex = (tid < LL) ? __expf(s - mx) : 0.0f;
        float sum = ex;
        for (int off = 16; off >= 1; off >>= 1) sum += __shfl_xor(sum, off);
        if (tid < LL) wt_lds[tid] = ex / sum;
    }
    __syncthreads();

    if (tid < DD) {
        float g = 0.0f;
        #pragma unroll 4
        for (int l = 0; l < LL; ++l) g += wt_lds[l] * mem_lds[l * 129 + tid];
        float me = g + mash_lds[tid];
        float sv = svc_lds[tid];
        new_lds[tid]          = me * sv;
        new_lds[DD + tid]     = me;
        new_lds[2 * DD + tid] = sv;
    }
    __syncthreads();

    if (tid < 8) {
        float acc = pred_b1[tid];
        for (int k = 0; k < 3 * DD; ++k) acc += new_lds[k] * pred_w1[k * 8 + tid];
        acc = fmaxf(acc, 0.0f);
        hp_lds[tid] = acc * pred_w2[tid];
    }
    __syncthreads();

    if (tid == 0) {
        float z = pred_b2[0];
        for (int j = 0; j < 8; ++j) z += hp_lds[j];
        out[b] = 1.0f / (1.0f + __expf(-z));
    }
}

// ---------------------------------------------------------------------------
extern "C" void kernel_launch(void* const* d_in, const int* in_sizes, int n_in,
                              void* d_out, int out_size, void* d_ws, size_t ws_size,
                              hipStream_t stream) {
    const int*   mashup_inputs  = (const int*)  d_in[0];
    const int*   service_inputs = (const int*)  d_in[1];
    const int*   member_masked  = (const int*)  d_in[2];
    const float* mask           = (const float*)d_in[3];
    const int*   adj_rows       = (const int*)  d_in[4];
    const int*   adj_cols       = (const int*)  d_in[5];
    const float* adj_vals       = (const float*)d_in[6];
    const int*   A_rows         = (const int*)  d_in[7];
    const int*   A_cols         = (const int*)  d_in[8];
    const float* A_vals         = (const float*)d_in[9];
    const float* d_inv          = (const float*)d_in[10];
    const float* user_tbl       = (const float*)d_in[11];
    const float* service_tbl    = (const float*)d_in[12];
    const float* mashup_tbl     = (const float*)d_in[13];
    const float* att_w1         = (const float*)d_in[14];
    const float* att_b1         = (const float*)d_in[15];
    const float* att_w2         = (const float*)d_in[16];
    const float* att_b2         = (const float*)d_in[17];
    const float* pred_w1        = (const float*)d_in[18];
    const float* pred_b1        = (const float*)d_in[19];
    const float* pred_w2        = (const float*)d_in[20];
    const float* pred_b2        = (const float*)d_in[21];

    const int E_ui = in_sizes[4];
    const int E_mm = in_sizes[7];
    const int B    = in_sizes[0];

    const int N_UI2  = NBUK_UI * NCH;              // 100032
    const int N_MM2  = NBUK_MM * NCH;              // 30016
    const int NB_UI  = (N_UI2 + 1023) / 1024;      // 98
    const int NB_MM  = (N_MM2 + 1023) / 1024;      // 30
    const int csz_ui = (E_ui + NCH - 1) / NCH;
    const int csz_mm = (E_mm + NCH - 1) / NCH;

    // ---- workspace layout ----
    uint2*    cvA    = (uint2*)d_ws;                           // E_ui (reused for MM pass A)
    uint2*    cvB_mm = cvA + E_mm;                             // E_mm (aliases tail of cvA region: disjoint from MM passA [0,E_mm))
    uint2*    cvB_ui = cvA + E_ui;                             // E_ui
    int*      h_ui   = (int*)(cvB_ui + E_ui);                  // N_UI2
    int*      s_ui   = h_ui + N_UI2;                           // N_UI2+1 (+pad)
    int*      h_mm   = s_ui + N_UI2 + 4;                       // N_MM2
    int*      s_mm   = h_mm + N_MM2;                           // N_MM2+1 (+pad)
    int*      bs     = s_mm + N_MM2 + 4;                       // 256
    int*      rp_ui  = bs + 256;                               // UIN_+1 (+pad)
    int*      rp_mm  = rp_ui + UIN_ + 4;                       // NM_+1 (+pad)
    ushort16* ui_bf  = (ushort16*)(rp_mm + NM_ + 4);           // UIN*128
    ushort16* h1     = ui_bf + (size_t)UIN_ * DD;
    ushort16* h2     = h1    + (size_t)UIN_ * DD;              // ui_final
    ushort16* mash_bf= h2    + (size_t)UIN_ * DD;
    ushort16* m1     = mash_bf + (size_t)NM_ * DD;
    ushort16* m2     = m1    + (size_t)NM_ * DD;               // mash_final

    // ---- bf16 conversion of base tables ----
    convert_kernel<<<2048, 256, 0, stream>>>(user_tbl, service_tbl, NU_,
                                             (uint32*)ui_bf, (size_t)UIN_ * DD / 2);
    convert_kernel<<<1024, 256, 0, stream>>>(mashup_tbl, mashup_tbl, NM_,
                                             (uint32*)mash_bf, (size_t)NM_ * DD / 2);

    // ---- UI edge build: hist -> scan -> bucket scatter -> exact sort ----
    bucket_histA<NBUK_UI><<<NCH, 256, 0, stream>>>(adj_rows, E_ui, csz_ui, h_ui);
    scan_blocksum<<<NB_UI, 256, 0, stream>>>(h_ui, bs, N_UI2);
    scan_final<<<NB_UI, 256, 0, stream>>>(h_ui, bs, s_ui, s_ui, N_UI2);
    bucket_scatterA<NBUK_UI><<<NCH, 256, 0, stream>>>(adj_rows, adj_cols, adj_vals,
                                                      s_ui, E_ui, csz_ui, cvA);
    sort_bucket<<<NBUK_UI, 256, 0, stream>>>(cvA, s_ui, cvB_ui, rp_ui, UIN_);

    // ---- MM edge build (cvA region reused for pass A) ----
    bucket_histA<NBUK_MM><<<NCH, 256, 0, stream>>>(A_rows, E_mm, csz_mm, h_mm);
    scan_blocksum<<<NB_MM, 256, 0, stream>>>(h_mm, bs, N_MM2);
    scan_final<<<NB_MM, 256, 0, stream>>>(h_mm, bs, s_mm, s_mm, N_MM2);
    bucket_scatterA<NBUK_MM><<<NCH, 256, 0, stream>>>(A_rows, A_cols, A_vals,
                                                      s_mm, E_mm, csz_mm, cvA);
    sort_bucket<<<NBUK_MM, 256, 0, stream>>>(cvA, s_mm, cvB_mm, rp_mm, NM_);

    // ---- user/service LightGCN propagation (2 layers, pull, bf16) ----
    const int ui_blocks = (UIN_ + 3) / 4;
    pull_kernel<0><<<ui_blocks, 256, 0, stream>>>(
        rp_ui, cvB_ui, ui_bf, nullptr, nullptr, nullptr, h1, UIN_);
    pull_kernel<2><<<ui_blocks, 256, 0, stream>>>(
        rp_ui, cvB_ui, h1, nullptr, ui_bf, h1, h2, UIN_);

    // ---- mashup propagation (2 layers, pull, d_inv fused, bf16) ----
    const int mm_blocks = (NM_ + 3) / 4;
    pull_kernel<1><<<mm_blocks, 256, 0, stream>>>(
        rp_mm, cvB_mm, mash_bf, d_inv, nullptr, nullptr, m1, NM_);
    pull_kernel<3><<<mm_blocks, 256, 0, stream>>>(
        rp_mm, cvB_mm, m1, d_inv, mash_bf, m1, m2, NM_);

    // ---- attention + prediction tail ----
    attn_pred_kernel<<<B, 512, 0, stream>>>(
        mashup_inputs, service_inputs, member_masked, mask,
        h2, m2,
        att_w1, att_b1, att_w2, att_b2,
        pred_w1, pred_b1, pred_w2, pred_b2,
        (float*)d_out);
}

// Round 7
// 319.512 us; speedup vs baseline: 9.7284x; 1.2370x over previous
//
#include <hip/hip_runtime.h>
#include <climits>

#define NU_ 80000
#define NS_ 20000
#define NM_ 30000
#define UIN_ (NU_ + NS_)
#define DD 128
#define LL 32
#define RPB 64                                   // rows per bucket
#define NCH 256                                  // chunks per graph
#define NBUK_UI ((UIN_ + RPB - 1) / RPB)         // 1563
#define NBUK_MM ((NM_  + RPB - 1) / RPB)         // 469

typedef unsigned int   uint32;
typedef unsigned short ushort16;

__device__ __forceinline__ float bflo(uint32 u) { return __uint_as_float(u << 16); }
__device__ __forceinline__ float bfhi(uint32 u) { return __uint_as_float(u & 0xffff0000u); }
__device__ __forceinline__ ushort16 f2bf(float f) {
    uint32 u = __float_as_uint(f);
    return (ushort16)((u + 0x7fffu + ((u >> 16) & 1u)) >> 16);   // RNE
}
__device__ __forceinline__ uint32 pack2bf(float lo, float hi) {
    return (uint32)f2bf(lo) | ((uint32)f2bf(hi) << 16);
}

// ---------------------------------------------------------------------------
// fp32 (split tables) -> packed bf16 table. n2 = total element pairs.
// ---------------------------------------------------------------------------
__global__ void convert_kernel(const float* __restrict__ srcA, const float* __restrict__ srcB,
                               int split_rows, uint32* __restrict__ dst, size_t n2) {
    size_t stride = (size_t)gridDim.x * blockDim.x;
    const size_t split_e = (size_t)split_rows * DD;
    for (size_t i = (size_t)blockIdx.x * blockDim.x + threadIdx.x; i < n2; i += stride) {
        size_t e = i * 2;
        const float* s = (e < split_e) ? (srcA + e) : (srcB + (e - split_e));
        float2 v = *reinterpret_cast<const float2*>(s);
        dst[i] = pack2bf(v.x, v.y);
    }
}

// ---------------------------------------------------------------------------
// Stage 1: per-chunk bucket histogram, bucket-major output h[b*NCH + c].
// 1024 threads (4 waves/SIMD) + unroll-4 batched loads for latency hiding.
// ---------------------------------------------------------------------------
template <int NBUK>
__global__ __launch_bounds__(1024) void bucket_histA(const int* __restrict__ rows, int E,
                                                     int csz, int* __restrict__ h) {
    __shared__ int hist[NBUK];
    for (int i = threadIdx.x; i < NBUK; i += 1024) hist[i] = 0;
    __syncthreads();
    const int c  = blockIdx.x;
    const int lo = c * csz, hi = min(lo + csz, E);
    int i = lo + threadIdx.x;
    for (; i + 3 * 1024 < hi; i += 4 * 1024) {
        int r0 = rows[i];
        int r1 = rows[i + 1024];
        int r2 = rows[i + 2048];
        int r3 = rows[i + 3072];
        atomicAdd(&hist[r0 >> 6], 1);
        atomicAdd(&hist[r1 >> 6], 1);
        atomicAdd(&hist[r2 >> 6], 1);
        atomicAdd(&hist[r3 >> 6], 1);
    }
    for (; i < hi; i += 1024) atomicAdd(&hist[rows[i] >> 6], 1);
    __syncthreads();
    for (int b = threadIdx.x; b < NBUK; b += 1024)
        h[b * NCH + c] = hist[b];
}

// ---------------------------------------------------------------------------
// Stage 2: multi-block exclusive scan (from round 3).
// ---------------------------------------------------------------------------
__global__ __launch_bounds__(256) void scan_blocksum(const int* __restrict__ cnt,
                                                     int* __restrict__ bsum, int n) {
    __shared__ int red[256];
    int base = blockIdx.x * 1024 + threadIdx.x * 4;
    int s = 0;
    if (base + 3 < n) {
        int4 v = *reinterpret_cast<const int4*>(cnt + base);
        s = v.x + v.y + v.z + v.w;
    } else {
        for (int i = base; i < n && i < base + 4; ++i) s += cnt[i];
    }
    red[threadIdx.x] = s;
    __syncthreads();
    for (int off = 128; off >= 1; off >>= 1) {
        if (threadIdx.x < off) red[threadIdx.x] += red[threadIdx.x + off];
        __syncthreads();
    }
    if (threadIdx.x == 0) bsum[blockIdx.x] = red[0];
}

__global__ __launch_bounds__(256) void scan_final(const int* __restrict__ cnt,
                                                  const int* __restrict__ bsum,
                                                  int* __restrict__ row_ptr,
                                                  int* __restrict__ cursor, int n) {
    __shared__ int lds[256];
    __shared__ int blk_off_s;
    const int tid = threadIdx.x;
    const int b   = blockIdx.x;

    int s = 0;
    for (int j = tid; j < b; j += 256) s += bsum[j];
    lds[tid] = s;
    __syncthreads();
    for (int off = 128; off >= 1; off >>= 1) {
        if (tid < off) lds[tid] += lds[tid + off];
        __syncthreads();
    }
    if (tid == 0) blk_off_s = lds[0];
    __syncthreads();
    const int blk_off = blk_off_s;

    int base = b * 1024 + tid * 4;
    int c0 = 0, c1 = 0, c2 = 0, c3 = 0;
    if (base + 3 < n) {
        int4 v = *reinterpret_cast<const int4*>(cnt + base);
        c0 = v.x; c1 = v.y; c2 = v.z; c3 = v.w;
    } else {
        if (base     < n) c0 = cnt[base];
        if (base + 1 < n) c1 = cnt[base + 1];
        if (base + 2 < n) c2 = cnt[base + 2];
        if (base + 3 < n) c3 = cnt[base + 3];
    }
    int tsum = c0 + c1 + c2 + c3;
    __syncthreads();
    lds[tid] = tsum;
    __syncthreads();
    for (int off = 1; off < 256; off <<= 1) {
        int v = (tid >= off) ? lds[tid - off] : 0;
        __syncthreads();
        lds[tid] += v;
        __syncthreads();
    }
    int p0 = blk_off + ((tid > 0) ? lds[tid - 1] : 0);
    int p1 = p0 + c0, p2 = p1 + c1, p3 = p2 + c2, p4 = p3 + c3;

    if (base     < n) { row_ptr[base]     = p0; cursor[base]     = p0; if (base     == n - 1) row_ptr[n] = p1; }
    if (base + 1 < n) { row_ptr[base + 1] = p1; cursor[base + 1] = p1; if (base + 1 == n - 1) row_ptr[n] = p2; }
    if (base + 2 < n) { row_ptr[base + 2] = p2; cursor[base + 2] = p2; if (base + 2 == n - 1) row_ptr[n] = p3; }
    if (base + 3 < n) { row_ptr[base + 3] = p3; cursor[base + 3] = p3; if (base + 3 == n - 1) row_ptr[n] = p4; }
}

// ---------------------------------------------------------------------------
// Stage 3: per-chunk scatter into bucket-grouped cvA. LDS cursors seeded from
// the scanned bucket-major offsets. 1024 threads + unroll-4 batched loads.
// cvA entry: x = col | (row_local << 25), y = val bits.
// ---------------------------------------------------------------------------
template <int NBUK>
__global__ __launch_bounds__(1024) void bucket_scatterA(
    const int* __restrict__ rows, const int* __restrict__ cols,
    const float* __restrict__ vals, const int* __restrict__ s,
    int E, int csz, uint2* __restrict__ cvA) {
    __shared__ int cur[NBUK];
    const int c = blockIdx.x;
    for (int b = threadIdx.x; b < NBUK; b += 1024) cur[b] = s[b * NCH + c];
    __syncthreads();
    const int lo = c * csz, hi = min(lo + csz, E);
    int i = lo + threadIdx.x;
    for (; i + 3 * 1024 < hi; i += 4 * 1024) {
        int   r0 = rows[i],        r1 = rows[i + 1024];
        int   r2 = rows[i + 2048], r3 = rows[i + 3072];
        int   q0 = cols[i],        q1 = cols[i + 1024];
        int   q2 = cols[i + 2048], q3 = cols[i + 3072];
        float v0 = vals[i],        v1 = vals[i + 1024];
        float v2 = vals[i + 2048], v3 = vals[i + 3072];
        int p0 = atomicAdd(&cur[r0 >> 6], 1);
        int p1 = atomicAdd(&cur[r1 >> 6], 1);
        int p2 = atomicAdd(&cur[r2 >> 6], 1);
        int p3 = atomicAdd(&cur[r3 >> 6], 1);
        cvA[p0] = make_uint2((uint32)q0 | ((uint32)(r0 & 63) << 25), __float_as_uint(v0));
        cvA[p1] = make_uint2((uint32)q1 | ((uint32)(r1 & 63) << 25), __float_as_uint(v1));
        cvA[p2] = make_uint2((uint32)q2 | ((uint32)(r2 & 63) << 25), __float_as_uint(v2));
        cvA[p3] = make_uint2((uint32)q3 | ((uint32)(r3 & 63) << 25), __float_as_uint(v3));
    }
    for (; i < hi; i += 1024) {
        int r = rows[i];
        int pos = atomicAdd(&cur[r >> 6], 1);
        cvA[pos] = make_uint2((uint32)cols[i] | ((uint32)(r & 63) << 25),
                              __float_as_uint(vals[i]));
    }
}

// ---------------------------------------------------------------------------
// Stage 4: exact per-row sort within each bucket. One block per bucket.
// ---------------------------------------------------------------------------
__global__ __launch_bounds__(256) void sort_bucket(
    const uint2* __restrict__ cvA, const int* __restrict__ s,
    uint2* __restrict__ cvB, int* __restrict__ row_ptr, int nrows) {
    __shared__ int cnt[RPB];
    __shared__ int cur[RPB];
    const int b    = blockIdx.x;
    const int tid  = threadIdx.x;
    const int base = s[b * NCH];
    const int endb = s[(b + 1) * NCH];   // last bucket: sentinel s[NBUK*NCH]=E

    if (tid < RPB) cnt[tid] = 0;
    __syncthreads();
    for (int i = base + tid; i < endb; i += 256)
        atomicAdd(&cnt[cvA[i].x >> 25], 1);
    __syncthreads();
    if (tid < 64) {
        int c = cnt[tid];
        int x = c;
        #pragma unroll
        for (int off = 1; off < 64; off <<= 1) {
            int v = __shfl_up(x, off);
            if (tid >= off) x += v;
        }
        int excl = base + x - c;            // exclusive prefix + bucket base
        cur[tid] = excl;
        int grow = b * RPB + tid;
        if (grow <= nrows) row_ptr[grow] = excl;   // padding rows give row_ptr[n]=E
    }
    __syncthreads();
    for (int i = base + tid; i < endb; i += 256) {
        uint2 e = cvA[i];
        int rl  = (int)(e.x >> 25);
        int pos = atomicAdd(&cur[rl], 1);
        cvB[pos] = make_uint2(e.x & 0x1FFFFFFu, e.y);
    }
}

// ---------------------------------------------------------------------------
// Pull SpMM (bf16 tables): one wave per destination row, lane owns dims 2l,2l+1.
// MODE bit0: scale by d_inv[row]. MODE bit1: out=(orig+hprev+res)/3.
// ---------------------------------------------------------------------------
template <int MODE>
__global__ __launch_bounds__(256) void pull_kernel(
    const int* __restrict__ row_ptr, const uint2* __restrict__ cv,
    const ushort16* __restrict__ x,
    const float* __restrict__ d_inv,
    const ushort16* __restrict__ orig, const ushort16* __restrict__ hprev,
    ushort16* __restrict__ out, int n)
{
    const int wid  = (blockIdx.x * blockDim.x + threadIdx.x) >> 6;
    const int lane = threadIdx.x & 63;
    if (wid >= n) return;
    const int beg = row_ptr[wid];
    const int end = row_ptr[wid + 1];

    float ax0 = 0.f, ay0 = 0.f, ax1 = 0.f, ay1 = 0.f;
    float ax2 = 0.f, ay2 = 0.f, ax3 = 0.f, ay3 = 0.f;
    int e = beg;
    for (; e + 3 < end; e += 4) {
        uint2 p0 = cv[e],     p1 = cv[e + 1];
        uint2 p2 = cv[e + 2], p3 = cv[e + 3];
        uint32 g0 = *reinterpret_cast<const uint32*>(x + (((size_t)p0.x) << 7) + lane * 2);
        uint32 g1 = *reinterpret_cast<const uint32*>(x + (((size_t)p1.x) << 7) + lane * 2);
        uint32 g2 = *reinterpret_cast<const uint32*>(x + (((size_t)p2.x) << 7) + lane * 2);
        uint32 g3 = *reinterpret_cast<const uint32*>(x + (((size_t)p3.x) << 7) + lane * 2);
        float v0 = __uint_as_float(p0.y), v1 = __uint_as_float(p1.y);
        float v2 = __uint_as_float(p2.y), v3 = __uint_as_float(p3.y);
        ax0 += v0 * bflo(g0); ay0 += v0 * bfhi(g0);
        ax1 += v1 * bflo(g1); ay1 += v1 * bfhi(g1);
        ax2 += v2 * bflo(g2); ay2 += v2 * bfhi(g2);
        ax3 += v3 * bflo(g3); ay3 += v3 * bfhi(g3);
    }
    for (; e < end; ++e) {
        uint2 p0 = cv[e];
        uint32 g0 = *reinterpret_cast<const uint32*>(x + (((size_t)p0.x) << 7) + lane * 2);
        float v0 = __uint_as_float(p0.y);
        ax0 += v0 * bflo(g0); ay0 += v0 * bfhi(g0);
    }
    float accx = (ax0 + ax1) + (ax2 + ax3);
    float accy = (ay0 + ay1) + (ay2 + ay3);

    if (MODE & 1) { float s = d_inv[wid]; accx *= s; accy *= s; }
    if (MODE & 2) {
        const float inv3 = 1.0f / 3.0f;
        uint32 o = *reinterpret_cast<const uint32*>(orig  + (((size_t)wid) << 7) + lane * 2);
        uint32 h = *reinterpret_cast<const uint32*>(hprev + (((size_t)wid) << 7) + lane * 2);
        accx = (bflo(o) + bflo(h) + accx) * inv3;
        accy = (bfhi(o) + bfhi(h) + accy) * inv3;
    }
    *reinterpret_cast<uint32*>(out + (((size_t)wid) << 7) + lane * 2) = pack2bf(accx, accy);
}

// ---------------------------------------------------------------------------
// Attention + prediction tail: one block (512 threads) per batch element.
// ---------------------------------------------------------------------------
__global__ __launch_bounds__(512) void attn_pred_kernel(
    const int* __restrict__ mashup_inputs, const int* __restrict__ service_inputs,
    const int* __restrict__ member_masked, const float* __restrict__ mask,
    const ushort16* __restrict__ ui_final, const ushort16* __restrict__ mash_final,
    const float* __restrict__ att_w1, const float* __restrict__ att_b1,
    const float* __restrict__ att_w2, const float* __restrict__ att_b2,
    const float* __restrict__ pred_w1, const float* __restrict__ pred_b1,
    const float* __restrict__ pred_w2, const float* __restrict__ pred_b2,
    float* __restrict__ out)
{
    const int b   = blockIdx.x;
    const int tid = threadIdx.x;

    __shared__ float mem_lds[LL * 129];
    __shared__ float svc_lds[DD];
    __shared__ float mash_lds[DD];
    __shared__ float w1_lds[2 * DD * 16];
    __shared__ float hdnw_lds[LL * 16];
    __shared__ float wt_lds[LL];
    __shared__ float new_lds[3 * DD];
    __shared__ float hp_lds[8];
    __shared__ int   midx[LL];

    if (tid < LL) midx[tid] = member_masked[b * LL + tid];
    for (int i = tid; i < 2 * DD * 16; i += 512) w1_lds[i] = att_w1[i];
    if (tid < 64) {
        int sidx = service_inputs[b];
        uint32 u = *reinterpret_cast<const uint32*>(ui_final + (size_t)(NU_ + sidx) * DD + tid * 2);
        svc_lds[tid * 2]     = bflo(u);
        svc_lds[tid * 2 + 1] = bfhi(u);
    } else if (tid >= 448) {
        int t  = tid - 448;
        int mi = mashup_inputs[b];
        uint32 u = *reinterpret_cast<const uint32*>(mash_final + (size_t)mi * DD + t * 2);
        mash_lds[t * 2]     = bflo(u);
        mash_lds[t * 2 + 1] = bfhi(u);
    }
    __syncthreads();

    for (int i = tid; i < LL * 64; i += 512) {
        int l = i >> 6, dp = (i & 63) * 2;
        uint32 u = *reinterpret_cast<const uint32*>(ui_final + (size_t)midx[l] * DD + dp);
        mem_lds[l * 129 + dp]     = bflo(u);
        mem_lds[l * 129 + dp + 1] = bfhi(u);
    }
    __syncthreads();

    {
        int l = tid >> 4, j = tid & 15;
        float acc = att_b1[j];
        const float* m = &mem_lds[l * 129];
        #pragma unroll 4
        for (int k = 0; k < DD; ++k) acc += m[k] * w1_lds[k * 16 + j];
        #pragma unroll 4
        for (int k = 0; k < DD; ++k) acc += svc_lds[k] * w1_lds[(DD + k) * 16 + j];
        acc = fmaxf(acc, 0.0f);
        hdnw_lds[l * 16 + j] = acc * att_w2[j];
    }
    __syncthreads();

    if (tid < 64) {
        float s = -3.0e38f;
        if (tid < LL) {
            s = att_b2[0];
            for (int j = 0; j < 16; ++j) s += hdnw_lds[tid * 16 + j];
            if (mask[b * LL + tid] > 0.0f) s = -1.0e9f;
        }
        float mx = s;
        for (int off = 16; off >= 1; off >>= 1) mx = fmaxf(mx, __shfl_xor(mx, off));
        float ex = (tid < LL) ? __expf(s - mx) : 0.0f;
        float sum = ex;
        for (int off = 16; off >= 1; off >>= 1) sum += __shfl_xor(sum, off);
        if (tid < LL) wt_lds[tid] = ex / sum;
    }
    __syncthreads();

    if (tid < DD) {
        float g = 0.0f;
        #pragma unroll 4
        for (int l = 0; l < LL; ++l) g += wt_lds[l] * mem_lds[l * 129 + tid];
        float me = g + mash_lds[tid];
        float sv = svc_lds[tid];
        new_lds[tid]          = me * sv;
        new_lds[DD + tid]     = me;
        new_lds[2 * DD + tid] = sv;
    }
    __syncthreads();

    if (tid < 8) {
        float acc = pred_b1[tid];
        for (int k = 0; k < 3 * DD; ++k) acc += new_lds[k] * pred_w1[k * 8 + tid];
        acc = fmaxf(acc, 0.0f);
        hp_lds[tid] = acc * pred_w2[tid];
    }
    __syncthreads();

    if (tid == 0) {
        float z = pred_b2[0];
        for (int j = 0; j < 8; ++j) z += hp_lds[j];
        out[b] = 1.0f / (1.0f + __expf(-z));
    }
}

// ---------------------------------------------------------------------------
extern "C" void kernel_launch(void* const* d_in, const int* in_sizes, int n_in,
                              void* d_out, int out_size, void* d_ws, size_t ws_size,
                              hipStream_t stream) {
    const int*   mashup_inputs  = (const int*)  d_in[0];
    const int*   service_inputs = (const int*)  d_in[1];
    const int*   member_masked  = (const int*)  d_in[2];
    const float* mask           = (const float*)d_in[3];
    const int*   adj_rows       = (const int*)  d_in[4];
    const int*   adj_cols       = (const int*)  d_in[5];
    const float* adj_vals       = (const float*)d_in[6];
    const int*   A_rows         = (const int*)  d_in[7];
    const int*   A_cols         = (const int*)  d_in[8];
    const float* A_vals         = (const float*)d_in[9];
    const float* d_inv          = (const float*)d_in[10];
    const float* user_tbl       = (const float*)d_in[11];
    const float* service_tbl    = (const float*)d_in[12];
    const float* mashup_tbl     = (const float*)d_in[13];
    const float* att_w1         = (const float*)d_in[14];
    const float* att_b1         = (const float*)d_in[15];
    const float* att_w2         = (const float*)d_in[16];
    const float* att_b2         = (const float*)d_in[17];
    const float* pred_w1        = (const float*)d_in[18];
    const float* pred_b1        = (const float*)d_in[19];
    const float* pred_w2        = (const float*)d_in[20];
    const float* pred_b2        = (const float*)d_in[21];

    const int E_ui = in_sizes[4];
    const int E_mm = in_sizes[7];
    const int B    = in_sizes[0];

    const int N_UI2  = NBUK_UI * NCH;              // 400128
    const int N_MM2  = NBUK_MM * NCH;              // 120064
    const int NB_UI  = (N_UI2 + 1023) / 1024;      // 391
    const int NB_MM  = (N_MM2 + 1023) / 1024;      // 118
    const int csz_ui = (E_ui + NCH - 1) / NCH;
    const int csz_mm = (E_mm + NCH - 1) / NCH;

    // ---- workspace layout ----
    uint2*    cvA    = (uint2*)d_ws;                           // E_ui (reused for MM pass A)
    uint2*    cvB_mm = cvA + E_mm;                             // E_mm (inside cvA region, disjoint from MM passA [0,E_mm))
    uint2*    cvB_ui = cvA + E_ui;                             // E_ui
    int*      h_ui   = (int*)(cvB_ui + E_ui);                  // N_UI2
    int*      s_ui   = h_ui + N_UI2;                           // N_UI2+1 (+pad)
    int*      h_mm   = s_ui + N_UI2 + 4;                       // N_MM2
    int*      s_mm   = h_mm + N_MM2;                           // N_MM2+1 (+pad)
    int*      bs     = s_mm + N_MM2 + 4;                       // 512
    int*      rp_ui  = bs + 512;                               // UIN_+1 (+pad)
    int*      rp_mm  = rp_ui + UIN_ + 4;                       // NM_+1 (+pad)
    ushort16* ui_bf  = (ushort16*)(rp_mm + NM_ + 4);           // UIN*128
    ushort16* h1     = ui_bf + (size_t)UIN_ * DD;
    ushort16* h2     = h1    + (size_t)UIN_ * DD;              // ui_final
    ushort16* mash_bf= h2    + (size_t)UIN_ * DD;
    ushort16* m1     = mash_bf + (size_t)NM_ * DD;
    ushort16* m2     = m1    + (size_t)NM_ * DD;               // mash_final

    // ---- bf16 conversion of base tables ----
    convert_kernel<<<2048, 256, 0, stream>>>(user_tbl, service_tbl, NU_,
                                             (uint32*)ui_bf, (size_t)UIN_ * DD / 2);
    convert_kernel<<<1024, 256, 0, stream>>>(mashup_tbl, mashup_tbl, NM_,
                                             (uint32*)mash_bf, (size_t)NM_ * DD / 2);

    // ---- UI edge build: hist -> scan -> bucket scatter -> exact sort ----
    bucket_histA<NBUK_UI><<<NCH, 1024, 0, stream>>>(adj_rows, E_ui, csz_ui, h_ui);
    scan_blocksum<<<NB_UI, 256, 0, stream>>>(h_ui, bs, N_UI2);
    scan_final<<<NB_UI, 256, 0, stream>>>(h_ui, bs, s_ui, s_ui, N_UI2);
    bucket_scatterA<NBUK_UI><<<NCH, 1024, 0, stream>>>(adj_rows, adj_cols, adj_vals,
                                                       s_ui, E_ui, csz_ui, cvA);
    sort_bucket<<<NBUK_UI, 256, 0, stream>>>(cvA, s_ui, cvB_ui, rp_ui, UIN_);

    // ---- MM edge build (cvA region reused for pass A) ----
    bucket_histA<NBUK_MM><<<NCH, 1024, 0, stream>>>(A_rows, E_mm, csz_mm, h_mm);
    scan_blocksum<<<NB_MM, 256, 0, stream>>>(h_mm, bs, N_MM2);
    scan_final<<<NB_MM, 256, 0, stream>>>(h_mm, bs, s_mm, s_mm, N_MM2);
    bucket_scatterA<NBUK_MM><<<NCH, 1024, 0, stream>>>(A_rows, A_cols, A_vals,
                                                       s_mm, E_mm, csz_mm, cvA);
    sort_bucket<<<NBUK_MM, 256, 0, stream>>>(cvA, s_mm, cvB_mm, rp_mm, NM_);

    // ---- user/service LightGCN propagation (2 layers, pull, bf16) ----
    const int ui_blocks = (UIN_ + 3) / 4;
    pull_kernel<0><<<ui_blocks, 256, 0, stream>>>(
        rp_ui, cvB_ui, ui_bf, nullptr, nullptr, nullptr, h1, UIN_);
    pull_kernel<2><<<ui_blocks, 256, 0, stream>>>(
        rp_ui, cvB_ui, h1, nullptr, ui_bf, h1, h2, UIN_);

    // ---- mashup propagation (2 layers, pull, d_inv fused, bf16) ----
    const int mm_blocks = (NM_ + 3) / 4;
    pull_kernel<1><<<mm_blocks, 256, 0, stream>>>(
        rp_mm, cvB_mm, mash_bf, d_inv, nullptr, nullptr, m1, NM_);
    pull_kernel<3><<<mm_blocks, 256, 0, stream>>>(
        rp_mm, cvB_mm, m1, d_inv, mash_bf, m1, m2, NM_);

    // ---- attention + prediction tail ----
    attn_pred_kernel<<<B, 512, 0, stream>>>(
        mashup_inputs, service_inputs, member_masked, mask,
        h2, m2,
        att_w1, att_b1, att_w2, att_b2,
        pred_w1, pred_b1, pred_w2, pred_b2,
        (float*)d_out);
}

// Round 8
// 312.734 us; speedup vs baseline: 9.9392x; 1.0217x over previous
//
#include <hip/hip_runtime.h>
#include <climits>

#define NU_ 80000
#define NS_ 20000
#define NM_ 30000
#define UIN_ (NU_ + NS_)
#define DD 128
#define LL 32
#define RPB 64                                   // rows per bucket
#define NCH 256                                  // chunks per graph
#define NBUK_UI ((UIN_ + RPB - 1) / RPB)         // 1563
#define NBUK_MM ((NM_  + RPB - 1) / RPB)         // 469

#define F8_SCALE 512.0f
#define F8_INV   (1.0f / 512.0f)

typedef unsigned int   uint32;
typedef unsigned short ushort_t;
typedef unsigned char  uchar_t;
typedef float f32x2 __attribute__((ext_vector_type(2)));

__device__ __forceinline__ float bflo(uint32 u) { return __uint_as_float(u << 16); }
__device__ __forceinline__ float bfhi(uint32 u) { return __uint_as_float(u & 0xffff0000u); }
__device__ __forceinline__ uint32 f2bf(float f) {
    uint32 u = __float_as_uint(f);
    return (u + 0x7fffu + ((u >> 16) & 1u)) >> 16;   // RNE
}
__device__ __forceinline__ uint32 pack2bf(float lo, float hi) {
    return f2bf(lo) | (f2bf(hi) << 16);
}

// ---- OCP e4m3fn encode/decode (HW converts on gfx950, SW fallback) --------
__device__ __forceinline__ float dec1_f8(uint32 b) {
    uint32 em = b & 0x7fu;
    uint32 s  = (b & 0x80u) << 24;
    float vn = __uint_as_float(s | (((em >> 3) + 120u) << 23) | ((em & 7u) << 20));
    float vd = (float)(int)em * 0.001953125f;        // denormal: m * 2^-9
    vd = (b & 0x80u) ? -vd : vd;
    return (em >= 8u) ? vn : vd;
}
__device__ __forceinline__ uint32 enc1_f8(float f) {
    uint32 u = __float_as_uint(f);
    uint32 s = (u >> 31) << 7;
    float a = fabsf(f);
    if (a >= 448.0f) return s | 0x7Eu;
    if (a < 0.015625f) {                              // denormal region
        int m = (int)(a * 512.0f + 0.5f);             // 0..8 (8 == 2^-6, encodes as 0x08)
        return s | (uint32)m;
    }
    uint32 au = u & 0x7fffffffu;
    au += 0x7FFFFu + ((au >> 20) & 1u);               // RNE to 3 mantissa bits
    uint32 em = (((au >> 23) - 120u) << 3) | ((au >> 20) & 7u);
    if (em >= 0x7Fu) em = 0x7Eu;                      // never emit NaN; clamp to 448
    return s | em;
}
__device__ __forceinline__ f32x2 dec2_f8(uint32 u) {  // bytes 0,1 -> 2 floats
#if __has_builtin(__builtin_amdgcn_cvt_pk_f32_fp8)
    return __builtin_amdgcn_cvt_pk_f32_fp8(u, false);
#else
    f32x2 r; r.x = dec1_f8(u & 0xffu); r.y = dec1_f8((u >> 8) & 0xffu); return r;
#endif
}
__device__ __forceinline__ uint32 pack2f8(float lo, float hi) {
#if __has_builtin(__builtin_amdgcn_cvt_pk_fp8_f32)
    return (uint32)__builtin_amdgcn_cvt_pk_fp8_f32(lo, hi, 0, false) & 0xFFFFu;
#else
    return enc1_f8(lo) | (enc1_f8(hi) << 8);
#endif
}

// ---------------------------------------------------------------------------
// fp32 (split tables) -> bf16 table + scaled fp8 table. n2 = element pairs.
// ---------------------------------------------------------------------------
__global__ void convert_kernel(const float* __restrict__ srcA, const float* __restrict__ srcB,
                               int split_rows, uint32* __restrict__ dst_bf,
                               ushort_t* __restrict__ dst_f8, size_t n2) {
    size_t stride = (size_t)gridDim.x * blockDim.x;
    const size_t split_e = (size_t)split_rows * DD;
    for (size_t i = (size_t)blockIdx.x * blockDim.x + threadIdx.x; i < n2; i += stride) {
        size_t e = i * 2;
        const float* s = (e < split_e) ? (srcA + e) : (srcB + (e - split_e));
        float2 v = *reinterpret_cast<const float2*>(s);
        dst_bf[i] = pack2bf(v.x, v.y);
        dst_f8[i] = (ushort_t)pack2f8(v.x * F8_SCALE, v.y * F8_SCALE);
    }
}

// ---------------------------------------------------------------------------
// Stage 1: per-chunk bucket histogram, bucket-major output h[b*NCH + c].
// ---------------------------------------------------------------------------
template <int NBUK>
__global__ __launch_bounds__(1024) void bucket_histA(const int* __restrict__ rows, int E,
                                                     int csz, int* __restrict__ h) {
    __shared__ int hist[NBUK];
    for (int i = threadIdx.x; i < NBUK; i += 1024) hist[i] = 0;
    __syncthreads();
    const int c  = blockIdx.x;
    const int lo = c * csz, hi = min(lo + csz, E);
    int i = lo + threadIdx.x;
    for (; i + 3 * 1024 < hi; i += 4 * 1024) {
        int r0 = rows[i];
        int r1 = rows[i + 1024];
        int r2 = rows[i + 2048];
        int r3 = rows[i + 3072];
        atomicAdd(&hist[r0 >> 6], 1);
        atomicAdd(&hist[r1 >> 6], 1);
        atomicAdd(&hist[r2 >> 6], 1);
        atomicAdd(&hist[r3 >> 6], 1);
    }
    for (; i < hi; i += 1024) atomicAdd(&hist[rows[i] >> 6], 1);
    __syncthreads();
    for (int b = threadIdx.x; b < NBUK; b += 1024)
        h[b * NCH + c] = hist[b];
}

// ---------------------------------------------------------------------------
// Stage 2: multi-block exclusive scan.
// ---------------------------------------------------------------------------
__global__ __launch_bounds__(256) void scan_blocksum(const int* __restrict__ cnt,
                                                     int* __restrict__ bsum, int n) {
    __shared__ int red[256];
    int base = blockIdx.x * 1024 + threadIdx.x * 4;
    int s = 0;
    if (base + 3 < n) {
        int4 v = *reinterpret_cast<const int4*>(cnt + base);
        s = v.x + v.y + v.z + v.w;
    } else {
        for (int i = base; i < n && i < base + 4; ++i) s += cnt[i];
    }
    red[threadIdx.x] = s;
    __syncthreads();
    for (int off = 128; off >= 1; off >>= 1) {
        if (threadIdx.x < off) red[threadIdx.x] += red[threadIdx.x + off];
        __syncthreads();
    }
    if (threadIdx.x == 0) bsum[blockIdx.x] = red[0];
}

__global__ __launch_bounds__(256) void scan_final(const int* __restrict__ cnt,
                                                  const int* __restrict__ bsum,
                                                  int* __restrict__ row_ptr,
                                                  int* __restrict__ cursor, int n) {
    __shared__ int lds[256];
    __shared__ int blk_off_s;
    const int tid = threadIdx.x;
    const int b   = blockIdx.x;

    int s = 0;
    for (int j = tid; j < b; j += 256) s += bsum[j];
    lds[tid] = s;
    __syncthreads();
    for (int off = 128; off >= 1; off >>= 1) {
        if (tid < off) lds[tid] += lds[tid + off];
        __syncthreads();
    }
    if (tid == 0) blk_off_s = lds[0];
    __syncthreads();
    const int blk_off = blk_off_s;

    int base = b * 1024 + tid * 4;
    int c0 = 0, c1 = 0, c2 = 0, c3 = 0;
    if (base + 3 < n) {
        int4 v = *reinterpret_cast<const int4*>(cnt + base);
        c0 = v.x; c1 = v.y; c2 = v.z; c3 = v.w;
    } else {
        if (base     < n) c0 = cnt[base];
        if (base + 1 < n) c1 = cnt[base + 1];
        if (base + 2 < n) c2 = cnt[base + 2];
        if (base + 3 < n) c3 = cnt[base + 3];
    }
    int tsum = c0 + c1 + c2 + c3;
    __syncthreads();
    lds[tid] = tsum;
    __syncthreads();
    for (int off = 1; off < 256; off <<= 1) {
        int v = (tid >= off) ? lds[tid - off] : 0;
        __syncthreads();
        lds[tid] += v;
        __syncthreads();
    }
    int p0 = blk_off + ((tid > 0) ? lds[tid - 1] : 0);
    int p1 = p0 + c0, p2 = p1 + c1, p3 = p2 + c2, p4 = p3 + c3;

    if (base     < n) { row_ptr[base]     = p0; cursor[base]     = p0; if (base     == n - 1) row_ptr[n] = p1; }
    if (base + 1 < n) { row_ptr[base + 1] = p1; cursor[base + 1] = p1; if (base + 1 == n - 1) row_ptr[n] = p2; }
    if (base + 2 < n) { row_ptr[base + 2] = p2; cursor[base + 2] = p2; if (base + 2 == n - 1) row_ptr[n] = p3; }
    if (base + 3 < n) { row_ptr[base + 3] = p3; cursor[base + 3] = p3; if (base + 3 == n - 1) row_ptr[n] = p4; }
}

// ---------------------------------------------------------------------------
// Stage 3: per-chunk scatter into bucket-grouped cvA.
// ---------------------------------------------------------------------------
template <int NBUK>
__global__ __launch_bounds__(1024) void bucket_scatterA(
    const int* __restrict__ rows, const int* __restrict__ cols,
    const float* __restrict__ vals, const int* __restrict__ s,
    int E, int csz, uint2* __restrict__ cvA) {
    __shared__ int cur[NBUK];
    const int c = blockIdx.x;
    for (int b = threadIdx.x; b < NBUK; b += 1024) cur[b] = s[b * NCH + c];
    __syncthreads();
    const int lo = c * csz, hi = min(lo + csz, E);
    int i = lo + threadIdx.x;
    for (; i + 3 * 1024 < hi; i += 4 * 1024) {
        int   r0 = rows[i],        r1 = rows[i + 1024];
        int   r2 = rows[i + 2048], r3 = rows[i + 3072];
        int   q0 = cols[i],        q1 = cols[i + 1024];
        int   q2 = cols[i + 2048], q3 = cols[i + 3072];
        float v0 = vals[i],        v1 = vals[i + 1024];
        float v2 = vals[i + 2048], v3 = vals[i + 3072];
        int p0 = atomicAdd(&cur[r0 >> 6], 1);
        int p1 = atomicAdd(&cur[r1 >> 6], 1);
        int p2 = atomicAdd(&cur[r2 >> 6], 1);
        int p3 = atomicAdd(&cur[r3 >> 6], 1);
        cvA[p0] = make_uint2((uint32)q0 | ((uint32)(r0 & 63) << 25), __float_as_uint(v0));
        cvA[p1] = make_uint2((uint32)q1 | ((uint32)(r1 & 63) << 25), __float_as_uint(v1));
        cvA[p2] = make_uint2((uint32)q2 | ((uint32)(r2 & 63) << 25), __float_as_uint(v2));
        cvA[p3] = make_uint2((uint32)q3 | ((uint32)(r3 & 63) << 25), __float_as_uint(v3));
    }
    for (; i < hi; i += 1024) {
        int r = rows[i];
        int pos = atomicAdd(&cur[r >> 6], 1);
        cvA[pos] = make_uint2((uint32)cols[i] | ((uint32)(r & 63) << 25),
                              __float_as_uint(vals[i]));
    }
}

// ---------------------------------------------------------------------------
// Stage 4: exact per-row sort within each bucket.
// ---------------------------------------------------------------------------
__global__ __launch_bounds__(256) void sort_bucket(
    const uint2* __restrict__ cvA, const int* __restrict__ s,
    uint2* __restrict__ cvB, int* __restrict__ row_ptr, int nrows) {
    __shared__ int cnt[RPB];
    __shared__ int cur[RPB];
    const int b    = blockIdx.x;
    const int tid  = threadIdx.x;
    const int base = s[b * NCH];
    const int endb = s[(b + 1) * NCH];

    if (tid < RPB) cnt[tid] = 0;
    __syncthreads();
    for (int i = base + tid; i < endb; i += 256)
        atomicAdd(&cnt[cvA[i].x >> 25], 1);
    __syncthreads();
    if (tid < 64) {
        int c = cnt[tid];
        int x = c;
        #pragma unroll
        for (int off = 1; off < 64; off <<= 1) {
            int v = __shfl_up(x, off);
            if (tid >= off) x += v;
        }
        int excl = base + x - c;
        cur[tid] = excl;
        int grow = b * RPB + tid;
        if (grow <= nrows) row_ptr[grow] = excl;
    }
    __syncthreads();
    for (int i = base + tid; i < endb; i += 256) {
        uint2 e = cvA[i];
        int rl  = (int)(e.x >> 25);
        int pos = atomicAdd(&cur[rl], 1);
        cvB[pos] = make_uint2(e.x & 0x1FFFFFFu, e.y);
    }
}

// ---------------------------------------------------------------------------
// Pull SpMM over scaled fp8 tables. One wave per destination row, lane owns
// dims 2l,2l+1. Accumulator stays in the x512 scaled domain.
// MODE bit0: d_inv scale. MODE bit1: final combine -> bf16 out
//   out = (orig_bf + (hprev_f8 + acc) * F8_INV) / 3 ; else fp8 out (scaled).
// ---------------------------------------------------------------------------
template <int MODE>
__global__ __launch_bounds__(256) void pull_kernel(
    const int* __restrict__ row_ptr, const uint2* __restrict__ cv,
    const uchar_t* __restrict__ x,
    const float* __restrict__ d_inv,
    const uint32* __restrict__ orig_bf, const uchar_t* __restrict__ hprev_f8,
    void* __restrict__ out, int n)
{
    const int wid  = (blockIdx.x * blockDim.x + threadIdx.x) >> 6;
    const int lane = threadIdx.x & 63;
    if (wid >= n) return;
    const int beg = row_ptr[wid];
    const int end = row_ptr[wid + 1];
    const int loff = lane << 1;

    float ax0 = 0.f, ay0 = 0.f, ax1 = 0.f, ay1 = 0.f;
    float ax2 = 0.f, ay2 = 0.f, ax3 = 0.f, ay3 = 0.f;
    int e = beg;
    for (; e + 3 < end; e += 4) {
        uint2 p0 = cv[e],     p1 = cv[e + 1];
        uint2 p2 = cv[e + 2], p3 = cv[e + 3];
        uint32 g0 = *reinterpret_cast<const ushort_t*>(x + (((size_t)p0.x) << 7) + loff);
        uint32 g1 = *reinterpret_cast<const ushort_t*>(x + (((size_t)p1.x) << 7) + loff);
        uint32 g2 = *reinterpret_cast<const ushort_t*>(x + (((size_t)p2.x) << 7) + loff);
        uint32 g3 = *reinterpret_cast<const ushort_t*>(x + (((size_t)p3.x) << 7) + loff);
        float v0 = __uint_as_float(p0.y), v1 = __uint_as_float(p1.y);
        float v2 = __uint_as_float(p2.y), v3 = __uint_as_float(p3.y);
        f32x2 d0 = dec2_f8(g0), d1 = dec2_f8(g1);
        f32x2 d2 = dec2_f8(g2), d3 = dec2_f8(g3);
        ax0 += v0 * d0.x; ay0 += v0 * d0.y;
        ax1 += v1 * d1.x; ay1 += v1 * d1.y;
        ax2 += v2 * d2.x; ay2 += v2 * d2.y;
        ax3 += v3 * d3.x; ay3 += v3 * d3.y;
    }
    for (; e < end; ++e) {
        uint2 p0 = cv[e];
        uint32 g0 = *reinterpret_cast<const ushort_t*>(x + (((size_t)p0.x) << 7) + loff);
        float v0 = __uint_as_float(p0.y);
        f32x2 d0 = dec2_f8(g0);
        ax0 += v0 * d0.x; ay0 += v0 * d0.y;
    }
    float accx = (ax0 + ax1) + (ax2 + ax3);
    float accy = (ay0 + ay1) + (ay2 + ay3);

    if (MODE & 1) { float s = d_inv[wid]; accx *= s; accy *= s; }
    if (MODE & 2) {
        const float inv3 = 1.0f / 3.0f;
        uint32 o  = orig_bf[(size_t)wid * 64 + lane];
        uint32 hp = *reinterpret_cast<const ushort_t*>(hprev_f8 + (((size_t)wid) << 7) + loff);
        f32x2 h = dec2_f8(hp);
        float lo = (bflo(o) + (h.x + accx) * F8_INV) * inv3;
        float hi = (bfhi(o) + (h.y + accy) * F8_INV) * inv3;
        reinterpret_cast<uint32*>(out)[(size_t)wid * 64 + lane] = pack2bf(lo, hi);
    } else {
        // intermediate layer: store directly in scaled domain as fp8
        *reinterpret_cast<ushort_t*>((uchar_t*)out + (((size_t)wid) << 7) + loff) =
            (ushort_t)pack2f8(accx, accy);
    }
}

// ---------------------------------------------------------------------------
// Attention + prediction tail: one block (512 threads) per batch element.
// ui_final / mash_final are bf16-pair (uint32) tables.
// ---------------------------------------------------------------------------
__global__ __launch_bounds__(512) void attn_pred_kernel(
    const int* __restrict__ mashup_inputs, const int* __restrict__ service_inputs,
    const int* __restrict__ member_masked, const float* __restrict__ mask,
    const uint32* __restrict__ ui_final, const uint32* __restrict__ mash_final,
    const float* __restrict__ att_w1, const float* __restrict__ att_b1,
    const float* __restrict__ att_w2, const float* __restrict__ att_b2,
    const float* __restrict__ pred_w1, const float* __restrict__ pred_b1,
    const float* __restrict__ pred_w2, const float* __restrict__ pred_b2,
    float* __restrict__ out)
{
    const int b   = blockIdx.x;
    const int tid = threadIdx.x;

    __shared__ float mem_lds[LL * 129];
    __shared__ float svc_lds[DD];
    __shared__ float mash_lds[DD];
    __shared__ float w1_lds[2 * DD * 16];
    __shared__ float hdnw_lds[LL * 16];
    __shared__ float wt_lds[LL];
    __shared__ float new_lds[3 * DD];
    __shared__ float hp_lds[8];
    __shared__ int   midx[LL];

    if (tid < LL) midx[tid] = member_masked[b * LL + tid];
    for (int i = tid; i < 2 * DD * 16; i += 512) w1_lds[i] = att_w1[i];
    if (tid < 64) {
        int sidx = service_inputs[b];
        uint32 u = ui_final[(size_t)(NU_ + sidx) * 64 + tid];
        svc_lds[tid * 2]     = bflo(u);
        svc_lds[tid * 2 + 1] = bfhi(u);
    } else if (tid >= 448) {
        int t  = tid - 448;
        int mi = mashup_inputs[b];
        uint32 u = mash_final[(size_t)mi * 64 + t];
        mash_lds[t * 2]     = bflo(u);
        mash_lds[t * 2 + 1] = bfhi(u);
    }
    __syncthreads();

    for (int i = tid; i < LL * 64; i += 512) {
        int l = i >> 6, dp = (i & 63) * 2;
        uint32 u = ui_final[(size_t)midx[l] * 64 + (i & 63)];
        mem_lds[l * 129 + dp]     = bflo(u);
        mem_lds[l * 129 + dp + 1] = bfhi(u);
    }
    __syncthreads();

    {
        int l = tid >> 4, j = tid & 15;
        float acc = att_b1[j];
        const float* m = &mem_lds[l * 129];
        #pragma unroll 4
        for (int k = 0; k < DD; ++k) acc += m[k] * w1_lds[k * 16 + j];
        #pragma unroll 4
        for (int k = 0; k < DD; ++k) acc += svc_lds[k] * w1_lds[(DD + k) * 16 + j];
        acc = fmaxf(acc, 0.0f);
        hdnw_lds[l * 16 + j] = acc * att_w2[j];
    }
    __syncthreads();

    if (tid < 64) {
        float s = -3.0e38f;
        if (tid < LL) {
            s = att_b2[0];
            for (int j = 0; j < 16; ++j) s += hdnw_lds[tid * 16 + j];
            if (mask[b * LL + tid] > 0.0f) s = -1.0e9f;
        }
        float mx = s;
        for (int off = 16; off >= 1; off >>= 1) mx = fmaxf(mx, __shfl_xor(mx, off));
        float ex = (tid < LL) ? __expf(s - mx) : 0.0f;
        float sum = ex;
        for (int off = 16; off >= 1; off >>= 1) sum += __shfl_xor(sum, off);
        if (tid < LL) wt_lds[tid] = ex / sum;
    }
    __syncthreads();

    if (tid < DD) {
        float g = 0.0f;
        #pragma unroll 4
        for (int l = 0; l < LL; ++l) g += wt_lds[l] * mem_lds[l * 129 + tid];
        float me = g + mash_lds[tid];
        float sv = svc_lds[tid];
        new_lds[tid]          = me * sv;
        new_lds[DD + tid]     = me;
        new_lds[2 * DD + tid] = sv;
    }
    __syncthreads();

    if (tid < 8) {
        float acc = pred_b1[tid];
        for (int k = 0; k < 3 * DD; ++k) acc += new_lds[k] * pred_w1[k * 8 + tid];
        acc = fmaxf(acc, 0.0f);
        hp_lds[tid] = acc * pred_w2[tid];
    }
    __syncthreads();

    if (tid == 0) {
        float z = pred_b2[0];
        for (int j = 0; j < 8; ++j) z += hp_lds[j];
        out[b] = 1.0f / (1.0f + __expf(-z));
    }
}

// ---------------------------------------------------------------------------
extern "C" void kernel_launch(void* const* d_in, const int* in_sizes, int n_in,
                              void* d_out, int out_size, void* d_ws, size_t ws_size,
                              hipStream_t stream) {
    const int*   mashup_inputs  = (const int*)  d_in[0];
    const int*   service_inputs = (const int*)  d_in[1];
    const int*   member_masked  = (const int*)  d_in[2];
    const float* mask           = (const float*)d_in[3];
    const int*   adj_rows       = (const int*)  d_in[4];
    const int*   adj_cols       = (const int*)  d_in[5];
    const float* adj_vals       = (const float*)d_in[6];
    const int*   A_rows         = (const int*)  d_in[7];
    const int*   A_cols         = (const int*)  d_in[8];
    const float* A_vals         = (const float*)d_in[9];
    const float* d_inv          = (const float*)d_in[10];
    const float* user_tbl       = (const float*)d_in[11];
    const float* service_tbl    = (const float*)d_in[12];
    const float* mashup_tbl     = (const float*)d_in[13];
    const float* att_w1         = (const float*)d_in[14];
    const float* att_b1         = (const float*)d_in[15];
    const float* att_w2         = (const float*)d_in[16];
    const float* att_b2         = (const float*)d_in[17];
    const float* pred_w1        = (const float*)d_in[18];
    const float* pred_b1        = (const float*)d_in[19];
    const float* pred_w2        = (const float*)d_in[20];
    const float* pred_b2        = (const float*)d_in[21];

    const int E_ui = in_sizes[4];
    const int E_mm = in_sizes[7];
    const int B    = in_sizes[0];

    const int N_UI2  = NBUK_UI * NCH;              // 400128
    const int N_MM2  = NBUK_MM * NCH;              // 120064
    const int NB_UI  = (N_UI2 + 1023) / 1024;      // 391
    const int NB_MM  = (N_MM2 + 1023) / 1024;      // 118
    const int csz_ui = (E_ui + NCH - 1) / NCH;
    const int csz_mm = (E_mm + NCH - 1) / NCH;

    // ---- workspace layout ----
    uint2*   cvA     = (uint2*)d_ws;                           // E_ui (reused for MM pass A)
    uint2*   cvB_mm  = cvA + E_mm;                             // E_mm (disjoint from MM passA [0,E_mm))
    uint2*   cvB_ui  = cvA + E_ui;                             // E_ui
    int*     h_ui    = (int*)(cvB_ui + E_ui);                  // N_UI2
    int*     s_ui    = h_ui + N_UI2;                           // N_UI2+1 (+pad)
    int*     h_mm    = s_ui + N_UI2 + 4;                       // N_MM2
    int*     s_mm    = h_mm + N_MM2;                           // N_MM2+1 (+pad)
    int*     bs      = s_mm + N_MM2 + 4;                       // 512
    int*     rp_ui   = bs + 512;                               // UIN_+1 (+pad)
    int*     rp_mm   = rp_ui + UIN_ + 4;                       // NM_+1 (+pad)
    uint32*  ui_bf   = (uint32*)(rp_mm + NM_ + 4);             // UIN*64  (bf16 pairs)
    uint32*  mash_bf = ui_bf + (size_t)UIN_ * 64;              // NM*64
    uint32*  h2      = mash_bf + (size_t)NM_ * 64;             // UIN*64  (ui_final, bf16)
    uint32*  m2      = h2 + (size_t)UIN_ * 64;                 // NM*64   (mash_final, bf16)
    uchar_t* ui_f8   = (uchar_t*)(m2 + (size_t)NM_ * 64);      // UIN*128 (scaled fp8)
    uchar_t* h1_f8   = ui_f8 + (size_t)UIN_ * DD;              // UIN*128
    uchar_t* mash_f8 = h1_f8 + (size_t)UIN_ * DD;              // NM*128
    uchar_t* m1_f8   = mash_f8 + (size_t)NM_ * DD;             // NM*128

    // ---- table conversion: bf16 + scaled fp8 ----
    convert_kernel<<<2048, 256, 0, stream>>>(user_tbl, service_tbl, NU_,
                                             ui_bf, (ushort_t*)ui_f8, (size_t)UIN_ * DD / 2);
    convert_kernel<<<1024, 256, 0, stream>>>(mashup_tbl, mashup_tbl, NM_,
                                             mash_bf, (ushort_t*)mash_f8, (size_t)NM_ * DD / 2);

    // ---- UI edge build: hist -> scan -> bucket scatter -> exact sort ----
    bucket_histA<NBUK_UI><<<NCH, 1024, 0, stream>>>(adj_rows, E_ui, csz_ui, h_ui);
    scan_blocksum<<<NB_UI, 256, 0, stream>>>(h_ui, bs, N_UI2);
    scan_final<<<NB_UI, 256, 0, stream>>>(h_ui, bs, s_ui, s_ui, N_UI2);
    bucket_scatterA<NBUK_UI><<<NCH, 1024, 0, stream>>>(adj_rows, adj_cols, adj_vals,
                                                       s_ui, E_ui, csz_ui, cvA);
    sort_bucket<<<NBUK_UI, 256, 0, stream>>>(cvA, s_ui, cvB_ui, rp_ui, UIN_);

    // ---- MM edge build (cvA region reused for pass A) ----
    bucket_histA<NBUK_MM><<<NCH, 1024, 0, stream>>>(A_rows, E_mm, csz_mm, h_mm);
    scan_blocksum<<<NB_MM, 256, 0, stream>>>(h_mm, bs, N_MM2);
    scan_final<<<NB_MM, 256, 0, stream>>>(h_mm, bs, s_mm, s_mm, N_MM2);
    bucket_scatterA<NBUK_MM><<<NCH, 1024, 0, stream>>>(A_rows, A_cols, A_vals,
                                                       s_mm, E_mm, csz_mm, cvA);
    sort_bucket<<<NBUK_MM, 256, 0, stream>>>(cvA, s_mm, cvB_mm, rp_mm, NM_);

    // ---- user/service LightGCN propagation (2 layers, fp8 gather) ----
    const int ui_blocks = (UIN_ + 3) / 4;
    pull_kernel<0><<<ui_blocks, 256, 0, stream>>>(
        rp_ui, cvB_ui, ui_f8, nullptr, nullptr, nullptr, h1_f8, UIN_);
    pull_kernel<2><<<ui_blocks, 256, 0, stream>>>(
        rp_ui, cvB_ui, h1_f8, nullptr, ui_bf, h1_f8, h2, UIN_);

    // ---- mashup propagation (2 layers, d_inv fused, fp8 gather) ----
    const int mm_blocks = (NM_ + 3) / 4;
    pull_kernel<1><<<mm_blocks, 256, 0, stream>>>(
        rp_mm, cvB_mm, mash_f8, d_inv, nullptr, nullptr, m1_f8, NM_);
    pull_kernel<3><<<mm_blocks, 256, 0, stream>>>(
        rp_mm, cvB_mm, m1_f8, d_inv, mash_bf, m1_f8, m2, NM_);

    // ---- attention + prediction tail ----
    attn_pred_kernel<<<B, 512, 0, stream>>>(
        mashup_inputs, service_inputs, member_masked, mask,
        h2, m2,
        att_w1, att_b1, att_w2, att_b2,
        pred_w1, pred_b1, pred_w2, pred_b2,
        (float*)d_out);
}

// Round 9
// 261.829 us; speedup vs baseline: 11.8716x; 1.1944x over previous
//
#include <hip/hip_runtime.h>
#include <climits>

#define NU_ 80000
#define NS_ 20000
#define NM_ 30000
#define UIN_ (NU_ + NS_)
#define DD 128
#define LL 32
#define RPB 64                                   // rows per bucket
#define NCH 256                                  // chunks per graph
#define NBUK_UI ((UIN_ + RPB - 1) / RPB)         // 1563
#define NBUK_MM ((NM_  + RPB - 1) / RPB)         // 469

#define F8_SCALE 512.0f
#define F8_INV   (1.0f / 512.0f)

typedef unsigned int   uint32;
typedef unsigned short ushort_t;
typedef unsigned char  uchar_t;
typedef float f32x2 __attribute__((ext_vector_type(2)));

__device__ __forceinline__ float bflo(uint32 u) { return __uint_as_float(u << 16); }
__device__ __forceinline__ float bfhi(uint32 u) { return __uint_as_float(u & 0xffff0000u); }
__device__ __forceinline__ uint32 f2bf(float f) {
    uint32 u = __float_as_uint(f);
    return (u + 0x7fffu + ((u >> 16) & 1u)) >> 16;   // RNE
}
__device__ __forceinline__ uint32 pack2bf(float lo, float hi) {
    return f2bf(lo) | (f2bf(hi) << 16);
}

// ---- OCP e4m3fn encode/decode (HW converts on gfx950, SW fallback) --------
__device__ __forceinline__ float dec1_f8(uint32 b) {
    uint32 em = b & 0x7fu;
    uint32 s  = (b & 0x80u) << 24;
    float vn = __uint_as_float(s | (((em >> 3) + 120u) << 23) | ((em & 7u) << 20));
    float vd = (float)(int)em * 0.001953125f;        // denormal: m * 2^-9
    vd = (b & 0x80u) ? -vd : vd;
    return (em >= 8u) ? vn : vd;
}
__device__ __forceinline__ uint32 enc1_f8(float f) {
    uint32 u = __float_as_uint(f);
    uint32 s = (u >> 31) << 7;
    float a = fabsf(f);
    if (a >= 448.0f) return s | 0x7Eu;
    if (a < 0.015625f) {
        int m = (int)(a * 512.0f + 0.5f);
        return s | (uint32)m;
    }
    uint32 au = u & 0x7fffffffu;
    au += 0x7FFFFu + ((au >> 20) & 1u);
    uint32 em = (((au >> 23) - 120u) << 3) | ((au >> 20) & 7u);
    if (em >= 0x7Fu) em = 0x7Eu;
    return s | em;
}
__device__ __forceinline__ f32x2 dec2_f8(uint32 u) {   // bytes 0,1
#if __has_builtin(__builtin_amdgcn_cvt_pk_f32_fp8)
    return __builtin_amdgcn_cvt_pk_f32_fp8(u, false);
#else
    f32x2 r; r.x = dec1_f8(u & 0xffu); r.y = dec1_f8((u >> 8) & 0xffu); return r;
#endif
}
__device__ __forceinline__ f32x2 dec2_f8_hi(uint32 u) { // bytes 2,3
#if __has_builtin(__builtin_amdgcn_cvt_pk_f32_fp8)
    return __builtin_amdgcn_cvt_pk_f32_fp8(u, true);
#else
    f32x2 r; r.x = dec1_f8((u >> 16) & 0xffu); r.y = dec1_f8(u >> 24); return r;
#endif
}
__device__ __forceinline__ uint32 pack2f8(float lo, float hi) {
#if __has_builtin(__builtin_amdgcn_cvt_pk_fp8_f32)
    return (uint32)__builtin_amdgcn_cvt_pk_fp8_f32(lo, hi, 0, false) & 0xFFFFu;
#else
    return enc1_f8(lo) | (enc1_f8(hi) << 8);
#endif
}

// ---------------------------------------------------------------------------
// fp32 (split tables) -> bf16 table + scaled fp8 table. n2 = element pairs.
// ---------------------------------------------------------------------------
__global__ void convert_kernel(const float* __restrict__ srcA, const float* __restrict__ srcB,
                               int split_rows, uint32* __restrict__ dst_bf,
                               ushort_t* __restrict__ dst_f8, size_t n2) {
    size_t stride = (size_t)gridDim.x * blockDim.x;
    const size_t split_e = (size_t)split_rows * DD;
    for (size_t i = (size_t)blockIdx.x * blockDim.x + threadIdx.x; i < n2; i += stride) {
        size_t e = i * 2;
        const float* s = (e < split_e) ? (srcA + e) : (srcB + (e - split_e));
        float2 v = *reinterpret_cast<const float2*>(s);
        dst_bf[i] = pack2bf(v.x, v.y);
        dst_f8[i] = (ushort_t)pack2f8(v.x * F8_SCALE, v.y * F8_SCALE);
    }
}

// ---------------------------------------------------------------------------
// Stage 1: per-chunk bucket histogram, bucket-major output h[b*NCH + c].
// ---------------------------------------------------------------------------
template <int NBUK>
__global__ __launch_bounds__(1024) void bucket_histA(const int* __restrict__ rows, int E,
                                                     int csz, int* __restrict__ h) {
    __shared__ int hist[NBUK];
    for (int i = threadIdx.x; i < NBUK; i += 1024) hist[i] = 0;
    __syncthreads();
    const int c  = blockIdx.x;
    const int lo = c * csz, hi = min(lo + csz, E);
    int i = lo + threadIdx.x;
    for (; i + 3 * 1024 < hi; i += 4 * 1024) {
        int r0 = rows[i];
        int r1 = rows[i + 1024];
        int r2 = rows[i + 2048];
        int r3 = rows[i + 3072];
        atomicAdd(&hist[r0 >> 6], 1);
        atomicAdd(&hist[r1 >> 6], 1);
        atomicAdd(&hist[r2 >> 6], 1);
        atomicAdd(&hist[r3 >> 6], 1);
    }
    for (; i < hi; i += 1024) atomicAdd(&hist[rows[i] >> 6], 1);
    __syncthreads();
    for (int b = threadIdx.x; b < NBUK; b += 1024)
        h[b * NCH + c] = hist[b];
}

// ---------------------------------------------------------------------------
// Stage 2: multi-block exclusive scan.
// ---------------------------------------------------------------------------
__global__ __launch_bounds__(256) void scan_blocksum(const int* __restrict__ cnt,
                                                     int* __restrict__ bsum, int n) {
    __shared__ int red[256];
    int base = blockIdx.x * 1024 + threadIdx.x * 4;
    int s = 0;
    if (base + 3 < n) {
        int4 v = *reinterpret_cast<const int4*>(cnt + base);
        s = v.x + v.y + v.z + v.w;
    } else {
        for (int i = base; i < n && i < base + 4; ++i) s += cnt[i];
    }
    red[threadIdx.x] = s;
    __syncthreads();
    for (int off = 128; off >= 1; off >>= 1) {
        if (threadIdx.x < off) red[threadIdx.x] += red[threadIdx.x + off];
        __syncthreads();
    }
    if (threadIdx.x == 0) bsum[blockIdx.x] = red[0];
}

__global__ __launch_bounds__(256) void scan_final(const int* __restrict__ cnt,
                                                  const int* __restrict__ bsum,
                                                  int* __restrict__ row_ptr,
                                                  int* __restrict__ cursor, int n) {
    __shared__ int lds[256];
    __shared__ int blk_off_s;
    const int tid = threadIdx.x;
    const int b   = blockIdx.x;

    int s = 0;
    for (int j = tid; j < b; j += 256) s += bsum[j];
    lds[tid] = s;
    __syncthreads();
    for (int off = 128; off >= 1; off >>= 1) {
        if (tid < off) lds[tid] += lds[tid + off];
        __syncthreads();
    }
    if (tid == 0) blk_off_s = lds[0];
    __syncthreads();
    const int blk_off = blk_off_s;

    int base = b * 1024 + tid * 4;
    int c0 = 0, c1 = 0, c2 = 0, c3 = 0;
    if (base + 3 < n) {
        int4 v = *reinterpret_cast<const int4*>(cnt + base);
        c0 = v.x; c1 = v.y; c2 = v.z; c3 = v.w;
    } else {
        if (base     < n) c0 = cnt[base];
        if (base + 1 < n) c1 = cnt[base + 1];
        if (base + 2 < n) c2 = cnt[base + 2];
        if (base + 3 < n) c3 = cnt[base + 3];
    }
    int tsum = c0 + c1 + c2 + c3;
    __syncthreads();
    lds[tid] = tsum;
    __syncthreads();
    for (int off = 1; off < 256; off <<= 1) {
        int v = (tid >= off) ? lds[tid - off] : 0;
        __syncthreads();
        lds[tid] += v;
        __syncthreads();
    }
    int p0 = blk_off + ((tid > 0) ? lds[tid - 1] : 0);
    int p1 = p0 + c0, p2 = p1 + c1, p3 = p2 + c2, p4 = p3 + c3;

    if (base     < n) { row_ptr[base]     = p0; cursor[base]     = p0; if (base     == n - 1) row_ptr[n] = p1; }
    if (base + 1 < n) { row_ptr[base + 1] = p1; cursor[base + 1] = p1; if (base + 1 == n - 1) row_ptr[n] = p2; }
    if (base + 2 < n) { row_ptr[base + 2] = p2; cursor[base + 2] = p2; if (base + 2 == n - 1) row_ptr[n] = p3; }
    if (base + 3 < n) { row_ptr[base + 3] = p3; cursor[base + 3] = p3; if (base + 3 == n - 1) row_ptr[n] = p4; }
}

// ---------------------------------------------------------------------------
// Stage 3: per-chunk scatter into bucket-grouped cvA.
// ---------------------------------------------------------------------------
template <int NBUK>
__global__ __launch_bounds__(1024) void bucket_scatterA(
    const int* __restrict__ rows, const int* __restrict__ cols,
    const float* __restrict__ vals, const int* __restrict__ s,
    int E, int csz, uint2* __restrict__ cvA) {
    __shared__ int cur[NBUK];
    const int c = blockIdx.x;
    for (int b = threadIdx.x; b < NBUK; b += 1024) cur[b] = s[b * NCH + c];
    __syncthreads();
    const int lo = c * csz, hi = min(lo + csz, E);
    int i = lo + threadIdx.x;
    for (; i + 3 * 1024 < hi; i += 4 * 1024) {
        int   r0 = rows[i],        r1 = rows[i + 1024];
        int   r2 = rows[i + 2048], r3 = rows[i + 3072];
        int   q0 = cols[i],        q1 = cols[i + 1024];
        int   q2 = cols[i + 2048], q3 = cols[i + 3072];
        float v0 = vals[i],        v1 = vals[i + 1024];
        float v2 = vals[i + 2048], v3 = vals[i + 3072];
        int p0 = atomicAdd(&cur[r0 >> 6], 1);
        int p1 = atomicAdd(&cur[r1 >> 6], 1);
        int p2 = atomicAdd(&cur[r2 >> 6], 1);
        int p3 = atomicAdd(&cur[r3 >> 6], 1);
        cvA[p0] = make_uint2((uint32)q0 | ((uint32)(r0 & 63) << 25), __float_as_uint(v0));
        cvA[p1] = make_uint2((uint32)q1 | ((uint32)(r1 & 63) << 25), __float_as_uint(v1));
        cvA[p2] = make_uint2((uint32)q2 | ((uint32)(r2 & 63) << 25), __float_as_uint(v2));
        cvA[p3] = make_uint2((uint32)q3 | ((uint32)(r3 & 63) << 25), __float_as_uint(v3));
    }
    for (; i < hi; i += 1024) {
        int r = rows[i];
        int pos = atomicAdd(&cur[r >> 6], 1);
        cvA[pos] = make_uint2((uint32)cols[i] | ((uint32)(r & 63) << 25),
                              __float_as_uint(vals[i]));
    }
}

// ---------------------------------------------------------------------------
// Stage 4: exact per-row sort within each bucket.
// ---------------------------------------------------------------------------
__global__ __launch_bounds__(256) void sort_bucket(
    const uint2* __restrict__ cvA, const int* __restrict__ s,
    uint2* __restrict__ cvB, int* __restrict__ row_ptr, int nrows) {
    __shared__ int cnt[RPB];
    __shared__ int cur[RPB];
    const int b    = blockIdx.x;
    const int tid  = threadIdx.x;
    const int base = s[b * NCH];
    const int endb = s[(b + 1) * NCH];

    if (tid < RPB) cnt[tid] = 0;
    __syncthreads();
    for (int i = base + tid; i < endb; i += 256)
        atomicAdd(&cnt[cvA[i].x >> 25], 1);
    __syncthreads();
    if (tid < 64) {
        int c = cnt[tid];
        int x = c;
        #pragma unroll
        for (int off = 1; off < 64; off <<= 1) {
            int v = __shfl_up(x, off);
            if (tid >= off) x += v;
        }
        int excl = base + x - c;
        cur[tid] = excl;
        int grow = b * RPB + tid;
        if (grow <= nrows) row_ptr[grow] = excl;
    }
    __syncthreads();
    for (int i = base + tid; i < endb; i += 256) {
        uint2 e = cvA[i];
        int rl  = (int)(e.x >> 25);
        int pos = atomicAdd(&cur[rl], 1);
        cvB[pos] = make_uint2(e.x & 0x1FFFFFFu, e.y);
    }
}

// ---------------------------------------------------------------------------
// Pull SpMM over scaled fp8 tables — QUARTER-WAVE edges.
// One wave per destination row; each 16-lane quarter q processes edges
// beg+q, beg+q+4, ... Lane ql owns dims 8*ql..8*ql+7 (uint2 = 8 fp8 bytes).
// One gather instruction fetches 4 edges' rows; 2-deep unroll = 8 edges
// in flight. Epilogue: shfl_xor(16,32) cross-quarter reduce, lanes 0-15 write.
// MODE bit0: d_inv scale. MODE bit1: bf16 combine out; else fp8 (scaled) out.
// ---------------------------------------------------------------------------
template <int MODE>
__global__ __launch_bounds__(256) void pull_kernel(
    const int* __restrict__ row_ptr, const uint2* __restrict__ cv,
    const uchar_t* __restrict__ x,
    const float* __restrict__ d_inv,
    const uint32* __restrict__ orig_bf, const uchar_t* __restrict__ hprev_f8,
    void* __restrict__ out, int n)
{
    const int wid  = (blockIdx.x * blockDim.x + threadIdx.x) >> 6;
    const int lane = threadIdx.x & 63;
    const int q    = lane >> 4;          // quarter 0..3 (edge slot)
    const int ql   = lane & 15;          // lane within quarter (dim block)
    if (wid >= n) return;
    const int beg = row_ptr[wid];
    const int end = row_ptr[wid + 1];
    const int boff = ql << 3;            // byte offset of this lane's 8 dims

    float a0 = 0.f, a1 = 0.f, a2 = 0.f, a3 = 0.f;
    float a4 = 0.f, a5 = 0.f, a6 = 0.f, a7 = 0.f;

    int e = beg + q;
    for (; e + 4 < end; e += 8) {
        uint2 pa = cv[e];
        uint2 pb = cv[e + 4];
        uint2 ga = *reinterpret_cast<const uint2*>(x + (((size_t)pa.x) << 7) + boff);
        uint2 gb = *reinterpret_cast<const uint2*>(x + (((size_t)pb.x) << 7) + boff);
        float va = __uint_as_float(pa.y);
        float vb = __uint_as_float(pb.y);
        f32x2 d0 = dec2_f8(ga.x), d1 = dec2_f8_hi(ga.x);
        f32x2 d2 = dec2_f8(ga.y), d3 = dec2_f8_hi(ga.y);
        a0 += va * d0.x; a1 += va * d0.y; a2 += va * d1.x; a3 += va * d1.y;
        a4 += va * d2.x; a5 += va * d2.y; a6 += va * d3.x; a7 += va * d3.y;
        f32x2 e0 = dec2_f8(gb.x), e1 = dec2_f8_hi(gb.x);
        f32x2 e2 = dec2_f8(gb.y), e3 = dec2_f8_hi(gb.y);
        a0 += vb * e0.x; a1 += vb * e0.y; a2 += vb * e1.x; a3 += vb * e1.y;
        a4 += vb * e2.x; a5 += vb * e2.y; a6 += vb * e3.x; a7 += vb * e3.y;
    }
    if (e < end) {
        uint2 pa = cv[e];
        uint2 ga = *reinterpret_cast<const uint2*>(x + (((size_t)pa.x) << 7) + boff);
        float va = __uint_as_float(pa.y);
        f32x2 d0 = dec2_f8(ga.x), d1 = dec2_f8_hi(ga.x);
        f32x2 d2 = dec2_f8(ga.y), d3 = dec2_f8_hi(ga.y);
        a0 += va * d0.x; a1 += va * d0.y; a2 += va * d1.x; a3 += va * d1.y;
        a4 += va * d2.x; a5 += va * d2.y; a6 += va * d3.x; a7 += va * d3.y;
    }

    // cross-quarter reduce: lanes l, l^16, l^32, l^48 sum -> every lane total
    a0 += __shfl_xor(a0, 16); a0 += __shfl_xor(a0, 32);
    a1 += __shfl_xor(a1, 16); a1 += __shfl_xor(a1, 32);
    a2 += __shfl_xor(a2, 16); a2 += __shfl_xor(a2, 32);
    a3 += __shfl_xor(a3, 16); a3 += __shfl_xor(a3, 32);
    a4 += __shfl_xor(a4, 16); a4 += __shfl_xor(a4, 32);
    a5 += __shfl_xor(a5, 16); a5 += __shfl_xor(a5, 32);
    a6 += __shfl_xor(a6, 16); a6 += __shfl_xor(a6, 32);
    a7 += __shfl_xor(a7, 16); a7 += __shfl_xor(a7, 32);

    if (lane < 16) {
        if (MODE & 1) {
            float s = d_inv[wid];
            a0 *= s; a1 *= s; a2 *= s; a3 *= s;
            a4 *= s; a5 *= s; a6 *= s; a7 *= s;
        }
        if (MODE & 2) {
            const float inv3 = 1.0f / 3.0f;
            uint4 o = *reinterpret_cast<const uint4*>(orig_bf + (size_t)wid * 64 + (ql << 2));
            uint2 hp = *reinterpret_cast<const uint2*>(hprev_f8 + (((size_t)wid) << 7) + boff);
            f32x2 h0 = dec2_f8(hp.x), h1 = dec2_f8_hi(hp.x);
            f32x2 h2 = dec2_f8(hp.y), h3 = dec2_f8_hi(hp.y);
            uint4 r;
            r.x = pack2bf((bflo(o.x) + (h0.x + a0) * F8_INV) * inv3,
                          (bfhi(o.x) + (h0.y + a1) * F8_INV) * inv3);
            r.y = pack2bf((bflo(o.y) + (h1.x + a2) * F8_INV) * inv3,
                          (bfhi(o.y) + (h1.y + a3) * F8_INV) * inv3);
            r.z = pack2bf((bflo(o.z) + (h2.x + a4) * F8_INV) * inv3,
                          (bfhi(o.z) + (h2.y + a5) * F8_INV) * inv3);
            r.w = pack2bf((bflo(o.w) + (h3.x + a6) * F8_INV) * inv3,
                          (bfhi(o.w) + (h3.y + a7) * F8_INV) * inv3);
            *reinterpret_cast<uint4*>(reinterpret_cast<uint32*>(out) + (size_t)wid * 64 + (ql << 2)) = r;
        } else {
            uint2 r;
            r.x = pack2f8(a0, a1) | (pack2f8(a2, a3) << 16);
            r.y = pack2f8(a4, a5) | (pack2f8(a6, a7) << 16);
            *reinterpret_cast<uint2*>((uchar_t*)out + (((size_t)wid) << 7) + boff) = r;
        }
    }
}

// ---------------------------------------------------------------------------
// Attention + prediction tail: one block (512 threads) per batch element.
// ---------------------------------------------------------------------------
__global__ __launch_bounds__(512) void attn_pred_kernel(
    const int* __restrict__ mashup_inputs, const int* __restrict__ service_inputs,
    const int* __restrict__ member_masked, const float* __restrict__ mask,
    const uint32* __restrict__ ui_final, const uint32* __restrict__ mash_final,
    const float* __restrict__ att_w1, const float* __restrict__ att_b1,
    const float* __restrict__ att_w2, const float* __restrict__ att_b2,
    const float* __restrict__ pred_w1, const float* __restrict__ pred_b1,
    const float* __restrict__ pred_w2, const float* __restrict__ pred_b2,
    float* __restrict__ out)
{
    const int b   = blockIdx.x;
    const int tid = threadIdx.x;

    __shared__ float mem_lds[LL * 129];
    __shared__ float svc_lds[DD];
    __shared__ float mash_lds[DD];
    __shared__ float w1_lds[2 * DD * 16];
    __shared__ float hdnw_lds[LL * 16];
    __shared__ float wt_lds[LL];
    __shared__ float new_lds[3 * DD];
    __shared__ float hp_lds[8];
    __shared__ int   midx[LL];

    if (tid < LL) midx[tid] = member_masked[b * LL + tid];
    for (int i = tid; i < 2 * DD * 16; i += 512) w1_lds[i] = att_w1[i];
    if (tid < 64) {
        int sidx = service_inputs[b];
        uint32 u = ui_final[(size_t)(NU_ + sidx) * 64 + tid];
        svc_lds[tid * 2]     = bflo(u);
        svc_lds[tid * 2 + 1] = bfhi(u);
    } else if (tid >= 448) {
        int t  = tid - 448;
        int mi = mashup_inputs[b];
        uint32 u = mash_final[(size_t)mi * 64 + t];
        mash_lds[t * 2]     = bflo(u);
        mash_lds[t * 2 + 1] = bfhi(u);
    }
    __syncthreads();

    for (int i = tid; i < LL * 64; i += 512) {
        int l = i >> 6, dp = (i & 63) * 2;
        uint32 u = ui_final[(size_t)midx[l] * 64 + (i & 63)];
        mem_lds[l * 129 + dp]     = bflo(u);
        mem_lds[l * 129 + dp + 1] = bfhi(u);
    }
    __syncthreads();

    {
        int l = tid >> 4, j = tid & 15;
        float acc = att_b1[j];
        const float* m = &mem_lds[l * 129];
        #pragma unroll 4
        for (int k = 0; k < DD; ++k) acc += m[k] * w1_lds[k * 16 + j];
        #pragma unroll 4
        for (int k = 0; k < DD; ++k) acc += svc_lds[k] * w1_lds[(DD + k) * 16 + j];
        acc = fmaxf(acc, 0.0f);
        hdnw_lds[l * 16 + j] = acc * att_w2[j];
    }
    __syncthreads();

    if (tid < 64) {
        float s = -3.0e38f;
        if (tid < LL) {
            s = att_b2[0];
            for (int j = 0; j < 16; ++j) s += hdnw_lds[tid * 16 + j];
            if (mask[b * LL + tid] > 0.0f) s = -1.0e9f;
        }
        float mx = s;
        for (int off = 16; off >= 1; off >>= 1) mx = fmaxf(mx, __shfl_xor(mx, off));
        float ex = (tid < LL) ? __expf(s - mx) : 0.0f;
        float sum = ex;
        for (int off = 16; off >= 1; off >>= 1) sum += __shfl_xor(sum, off);
        if (tid < LL) wt_lds[tid] = ex / sum;
    }
    __syncthreads();

    if (tid < DD) {
        float g = 0.0f;
        #pragma unroll 4
        for (int l = 0; l < LL; ++l) g += wt_lds[l] * mem_lds[l * 129 + tid];
        float me = g + mash_lds[tid];
        float sv = svc_lds[tid];
        new_lds[tid]          = me * sv;
        new_lds[DD + tid]     = me;
        new_lds[2 * DD + tid] = sv;
    }
    __syncthreads();

    if (tid < 8) {
        float acc = pred_b1[tid];
        for (int k = 0; k < 3 * DD; ++k) acc += new_lds[k] * pred_w1[k * 8 + tid];
        acc = fmaxf(acc, 0.0f);
        hp_lds[tid] = acc * pred_w2[tid];
    }
    __syncthreads();

    if (tid == 0) {
        float z = pred_b2[0];
        for (int j = 0; j < 8; ++j) z += hp_lds[j];
        out[b] = 1.0f / (1.0f + __expf(-z));
    }
}

// ---------------------------------------------------------------------------
extern "C" void kernel_launch(void* const* d_in, const int* in_sizes, int n_in,
                              void* d_out, int out_size, void* d_ws, size_t ws_size,
                              hipStream_t stream) {
    const int*   mashup_inputs  = (const int*)  d_in[0];
    const int*   service_inputs = (const int*)  d_in[1];
    const int*   member_masked  = (const int*)  d_in[2];
    const float* mask           = (const float*)d_in[3];
    const int*   adj_rows       = (const int*)  d_in[4];
    const int*   adj_cols       = (const int*)  d_in[5];
    const float* adj_vals       = (const float*)d_in[6];
    const int*   A_rows         = (const int*)  d_in[7];
    const int*   A_cols         = (const int*)  d_in[8];
    const float* A_vals         = (const float*)d_in[9];
    const float* d_inv          = (const float*)d_in[10];
    const float* user_tbl       = (const float*)d_in[11];
    const float* service_tbl    = (const float*)d_in[12];
    const float* mashup_tbl     = (const float*)d_in[13];
    const float* att_w1         = (const float*)d_in[14];
    const float* att_b1         = (const float*)d_in[15];
    const float* att_w2         = (const float*)d_in[16];
    const float* att_b2         = (const float*)d_in[17];
    const float* pred_w1        = (const float*)d_in[18];
    const float* pred_b1        = (const float*)d_in[19];
    const float* pred_w2        = (const float*)d_in[20];
    const float* pred_b2        = (const float*)d_in[21];

    const int E_ui = in_sizes[4];
    const int E_mm = in_sizes[7];
    const int B    = in_sizes[0];

    const int N_UI2  = NBUK_UI * NCH;              // 400128
    const int N_MM2  = NBUK_MM * NCH;              // 120064
    const int NB_UI  = (N_UI2 + 1023) / 1024;      // 391
    const int NB_MM  = (N_MM2 + 1023) / 1024;      // 118
    const int csz_ui = (E_ui + NCH - 1) / NCH;
    const int csz_mm = (E_mm + NCH - 1) / NCH;

    // ---- workspace layout ----
    uint2*   cvA     = (uint2*)d_ws;                           // E_ui (reused for MM pass A)
    uint2*   cvB_mm  = cvA + E_mm;                             // E_mm (disjoint from MM passA [0,E_mm))
    uint2*   cvB_ui  = cvA + E_ui;                             // E_ui
    int*     h_ui    = (int*)(cvB_ui + E_ui);                  // N_UI2
    int*     s_ui    = h_ui + N_UI2;                           // N_UI2+1 (+pad)
    int*     h_mm    = s_ui + N_UI2 + 4;                       // N_MM2
    int*     s_mm    = h_mm + N_MM2;                           // N_MM2+1 (+pad)
    int*     bs      = s_mm + N_MM2 + 4;                       // 512
    int*     rp_ui   = bs + 512;                               // UIN_+1 (+pad)
    int*     rp_mm   = rp_ui + UIN_ + 4;                       // NM_+1 (+pad)
    uint32*  ui_bf   = (uint32*)(rp_mm + NM_ + 4);             // UIN*64  (bf16 pairs)
    uint32*  mash_bf = ui_bf + (size_t)UIN_ * 64;              // NM*64
    uint32*  h2      = mash_bf + (size_t)NM_ * 64;             // UIN*64  (ui_final, bf16)
    uint32*  m2      = h2 + (size_t)UIN_ * 64;                 // NM*64   (mash_final, bf16)
    uchar_t* ui_f8   = (uchar_t*)(m2 + (size_t)NM_ * 64);      // UIN*128 (scaled fp8)
    uchar_t* h1_f8   = ui_f8 + (size_t)UIN_ * DD;              // UIN*128
    uchar_t* mash_f8 = h1_f8 + (size_t)UIN_ * DD;              // NM*128
    uchar_t* m1_f8   = mash_f8 + (size_t)NM_ * DD;             // NM*128

    // ---- table conversion: bf16 + scaled fp8 ----
    convert_kernel<<<2048, 256, 0, stream>>>(user_tbl, service_tbl, NU_,
                                             ui_bf, (ushort_t*)ui_f8, (size_t)UIN_ * DD / 2);
    convert_kernel<<<1024, 256, 0, stream>>>(mashup_tbl, mashup_tbl, NM_,
                                             mash_bf, (ushort_t*)mash_f8, (size_t)NM_ * DD / 2);

    // ---- UI edge build: hist -> scan -> bucket scatter -> exact sort ----
    bucket_histA<NBUK_UI><<<NCH, 1024, 0, stream>>>(adj_rows, E_ui, csz_ui, h_ui);
    scan_blocksum<<<NB_UI, 256, 0, stream>>>(h_ui, bs, N_UI2);
    scan_final<<<NB_UI, 256, 0, stream>>>(h_ui, bs, s_ui, s_ui, N_UI2);
    bucket_scatterA<NBUK_UI><<<NCH, 1024, 0, stream>>>(adj_rows, adj_cols, adj_vals,
                                                       s_ui, E_ui, csz_ui, cvA);
    sort_bucket<<<NBUK_UI, 256, 0, stream>>>(cvA, s_ui, cvB_ui, rp_ui, UIN_);

    // ---- MM edge build (cvA region reused for pass A) ----
    bucket_histA<NBUK_MM><<<NCH, 1024, 0, stream>>>(A_rows, E_mm, csz_mm, h_mm);
    scan_blocksum<<<NB_MM, 256, 0, stream>>>(h_mm, bs, N_MM2);
    scan_final<<<NB_MM, 256, 0, stream>>>(h_mm, bs, s_mm, s_mm, N_MM2);
    bucket_scatterA<NBUK_MM><<<NCH, 1024, 0, stream>>>(A_rows, A_cols, A_vals,
                                                       s_mm, E_mm, csz_mm, cvA);
    sort_bucket<<<NBUK_MM, 256, 0, stream>>>(cvA, s_mm, cvB_mm, rp_mm, NM_);

    // ---- user/service LightGCN propagation (2 layers, fp8 quarter-wave) ----
    const int ui_blocks = (UIN_ + 3) / 4;
    pull_kernel<0><<<ui_blocks, 256, 0, stream>>>(
        rp_ui, cvB_ui, ui_f8, nullptr, nullptr, nullptr, h1_f8, UIN_);
    pull_kernel<2><<<ui_blocks, 256, 0, stream>>>(
        rp_ui, cvB_ui, h1_f8, nullptr, ui_bf, h1_f8, h2, UIN_);

    // ---- mashup propagation (2 layers, d_inv fused, fp8 quarter-wave) ----
    const int mm_blocks = (NM_ + 3) / 4;
    pull_kernel<1><<<mm_blocks, 256, 0, stream>>>(
        rp_mm, cvB_mm, mash_f8, d_inv, nullptr, nullptr, m1_f8, NM_);
    pull_kernel<3><<<mm_blocks, 256, 0, stream>>>(
        rp_mm, cvB_mm, m1_f8, d_inv, mash_bf, m1_f8, m2, NM_);

    // ---- attention + prediction tail ----
    attn_pred_kernel<<<B, 512, 0, stream>>>(
        mashup_inputs, service_inputs, member_masked, mask,
        h2, m2,
        att_w1, att_b1, att_w2, att_b2,
        pred_w1, pred_b1, pred_w2, pred_b2,
        (float*)d_out);
}